// Round 3
// baseline (205.617 us; speedup 1.0000x reference)
//
#include <hip/hip_runtime.h>
#include <hip/hip_bf16.h>
#include <cstdint>
#include <cstddef>

// Problem constants
#define B_   2
#define S_   2048
#define H_   1024
#define NH   16
#define DH   64
#define LOG2E 1.4426950408889634f
#define SCALE2 (0.125f * LOG2E)   // D^-0.5 * log2(e): softmax done in exp2 domain

typedef __hip_bfloat16 bf16;
typedef short bf16x8 __attribute__((ext_vector_type(8)));   // 8 bf16 in 4 VGPRs
typedef float f32x4 __attribute__((ext_vector_type(4)));

#define MFMA16(a, b, c) __builtin_amdgcn_mfma_f32_16x16x32_bf16((a), (b), (c), 0, 0, 0)

__device__ __forceinline__ void async16(const void* g, void* l) {
  __builtin_amdgcn_global_load_lds(
      (const __attribute__((address_space(1))) void*)g,
      (__attribute__((address_space(3))) void*)l,
      16, 0, 0);
}
__device__ __forceinline__ void async4(const void* g, void* l) {
  __builtin_amdgcn_global_load_lds(
      (const __attribute__((address_space(1))) void*)g,
      (__attribute__((address_space(3))) void*)l,
      4, 0, 0);
}

// ---------------------------------------------------------------------------
// Fused prep kernel (one dispatch, grid 8208) — unchanged from R1.
// ---------------------------------------------------------------------------
__device__ __forceinline__ void tr_body(const float* __restrict__ src,
                                        bf16* __restrict__ dst, int R, int C,
                                        int c0, int r0, bf16 (*tile)[33], int tid) {
  int tx = tid & 31, ty = tid >> 5;   // 32 x 8
  for (int i = 0; i < 32; i += 8)
    tile[ty + i][tx] = __float2bfloat16(src[(size_t)(r0 + ty + i) * C + c0 + tx]);
  __syncthreads();
  for (int i = 0; i < 32; i += 8)
    dst[(size_t)(c0 + ty + i) * R + r0 + tx] = tile[tx][ty + i];
}

__global__ __launch_bounds__(256)
void prep(const float* __restrict__ x, bf16* __restrict__ xb,
          const float* __restrict__ qkv, bf16* __restrict__ qkvT,
          const float* __restrict__ outw, bf16* __restrict__ outwT,
          const float* __restrict__ rpe, float* __restrict__ cum) {
  __shared__ char pm[2176] __attribute__((aligned(16)));
  const int L = blockIdx.x, tid = threadIdx.x;
  if (L < 4096) {
    int i = (L * 256 + tid) * 4;
    float4 v = *(const float4*)(x + i);
    bf16 o[4] = {__float2bfloat16(v.x), __float2bfloat16(v.y),
                 __float2bfloat16(v.z), __float2bfloat16(v.w)};
    *(uint64_t*)(xb + i) = *(const uint64_t*)o;
  } else if (L < 7168) {
    int t = L - 4096;
    int cx = t % 96, ry = t / 96;
    tr_body(qkv, qkvT, 1024, 3072, cx * 32, ry * 32, (bf16(*)[33])pm, tid);
  } else if (L < 8192) {
    int t = L - 7168;
    int cx = t & 31, ry = t >> 5;
    tr_body(outw, outwT, 1024, 1024, cx * 32, ry * 32, (bf16(*)[33])pm, tid);
  } else {
    // rpe cumsum (scaled by LOG2E)
    float* ssum = (float*)pm;
    int n = L - 8192;
    float loc[8];
    float s = 0.f;
    int base = tid * 8;
#pragma unroll
    for (int u = 0; u < 8; ++u) {
      loc[u] = rpe[n * S_ + base + u];
      s += loc[u];
    }
    ssum[tid] = s;
    __syncthreads();
    float own = s;
    for (int off = 1; off < 256; off <<= 1) {
      float v = (tid >= off) ? ssum[tid - off] : 0.f;
      __syncthreads();
      ssum[tid] += v;
      __syncthreads();
    }
    float run = ssum[tid] - own;   // exclusive prefix of this thread's chunk
#pragma unroll
    for (int u = 0; u < 8; ++u) {
      run += loc[u];
      cum[n * S_ + base + u] = run * LOG2E;
    }
  }
}

// ---------------------------------------------------------------------------
// GEMM — unchanged from R1.
// ---------------------------------------------------------------------------
template <int MODE>
__global__ __launch_bounds__(256, MODE == 0 ? 3 : 2)
void gemm_bt(const bf16* __restrict__ A, const bf16* __restrict__ Bt,
             bf16* __restrict__ C0, bf16* __restrict__ C1, bf16* __restrict__ C2,
             float* __restrict__ F0) {
  constexpr int NT = (MODE == 0) ? 4 : 2;     // n-subtiles per wave
  constexpr int NB = NT * 32;                 // block n-extent: 128 or 64
  __shared__ char smem[MODE == 0 ? 36864 : 12288] __attribute__((aligned(16)));
  bf16* As = (bf16*)smem;              // [128*32]
  bf16* Bs = (bf16*)(smem + 8192);     // [NB*32]
  const int tid = threadIdx.x, lane = tid & 63, w = tid >> 6;
  const int lr = lane & 15, lq = lane >> 4;
  const int m0 = blockIdx.y * 128, n0 = blockIdx.x * NB;
  const int wm = (w & 1) * 64, wn = (w >> 1) * (NT * 16);

  f32x4 acc[4][NT] = {};

  for (int k0 = 0; k0 < 1024; k0 += 32) {
    __syncthreads();
#pragma unroll
    for (int t = 0; t < 2; ++t) {
      int c = (t * 4 + w) * 64 + lane;          // 16B-chunk id 0..511
      int row = c >> 2, ch = c & 3;
      int k8 = (ch ^ ((row >> 1) & 3)) * 8;     // swizzled source chunk
      async16(A + (size_t)(m0 + row) * 1024 + k0 + k8,
              (char*)As + (size_t)(t * 4 + w) * 1024 + lane * 16);
    }
#pragma unroll
    for (int t = 0; t < NB / 64; ++t) {
      int c = (t * 4 + w) * 64 + lane;          // chunk id, NB*4 total
      int row = c >> 2, ch = c & 3;
      int k8 = (ch ^ ((row >> 1) & 3)) * 8;
      async16(Bt + (size_t)(n0 + row) * 1024 + k0 + k8,
              (char*)Bs + (size_t)(t * 4 + w) * 1024 + lane * 16);
    }
    __syncthreads();
    bf16x8 af[4], bfr[NT];
#pragma unroll
    for (int mt = 0; mt < 4; ++mt) {
      int row = wm + mt * 16 + lr;
      af[mt] = *(const bf16x8*)(As + row * 32 + ((lq ^ ((row >> 1) & 3)) << 3));
    }
#pragma unroll
    for (int nt = 0; nt < NT; ++nt) {
      int row = wn + nt * 16 + lr;
      bfr[nt] = *(const bf16x8*)(Bs + row * 32 + ((lq ^ ((row >> 1) & 3)) << 3));
    }
#pragma unroll
    for (int mt = 0; mt < 4; ++mt)
#pragma unroll
      for (int nt = 0; nt < NT; ++nt)
        acc[mt][nt] = MFMA16(af[mt], bfr[nt], acc[mt][nt]);
  }

  if (MODE == 0) {
    __syncthreads();   // all As/Bs reads done; reuse LDS for epilogue tiles
    bf16* E = (bf16*)smem + w * (64 * 72);   // wave-private [64][72]
    const int cbase = n0 + wn;               // 64-aligned
    const int mm = cbase >> 10, nn = (cbase >> 6) & 15;
    const int bb = (m0 + wm) >> 11;
    const int sbase = (m0 + wm) & 2047;
    if (mm < 2) {
      // write acc as [s][d] into E
#pragma unroll
      for (int mt = 0; mt < 4; ++mt)
#pragma unroll
        for (int nt = 0; nt < 4; ++nt)
#pragma unroll
          for (int r = 0; r < 4; ++r)
            E[(mt * 16 + lq * 4 + r) * 72 + nt * 16 + lr] =
                __float2bfloat16(acc[mt][nt][r]);
      // wave-private readback (in-wave lgkm ordering), b128 stores
      bf16* dst = (mm == 0 ? C0 : C1) +
                  ((size_t)(bb * NH + nn) * S_ + sbase) * DH;
#pragma unroll
      for (int it = 0; it < 8; ++it) {
        int c = it * 64 + lane;
        int rw = c >> 3, c8 = c & 7;
        *(uint4*)(dst + (size_t)rw * DH + c8 * 8) =
            *(const uint4*)(E + rw * 72 + c8 * 8);
      }
    } else {
      // V: write acc as [d][s] into E
#pragma unroll
      for (int mt = 0; mt < 4; ++mt)
#pragma unroll
        for (int nt = 0; nt < 4; ++nt)
#pragma unroll
          for (int r = 0; r < 4; ++r)
            E[(nt * 16 + lr) * 72 + mt * 16 + lq * 4 + r] =
                __float2bfloat16(acc[mt][nt][r]);
      bf16* dst = C2 + (size_t)(bb * NH + nn) * DH * S_;
#pragma unroll
      for (int it = 0; it < 8; ++it) {
        int c = it * 64 + lane;
        int dr = c >> 3, c8 = c & 7;
        *(uint4*)(dst + (size_t)dr * S_ + sbase + c8 * 8) =
            *(const uint4*)(E + dr * 72 + c8 * 8);
      }
    }
  } else {
#pragma unroll
    for (int mt = 0; mt < 4; ++mt)
#pragma unroll
      for (int nt = 0; nt < NT; ++nt)
#pragma unroll
        for (int r = 0; r < 4; ++r) {
          int rM = m0 + wm + mt * 16 + lq * 4 + r;
          int cN = n0 + wn + nt * 16 + lr;
          F0[(size_t)rM * 1024 + cN] = acc[mt][nt][r];
        }
  }
}

// ---------------------------------------------------------------------------
// Flash attention, R2 structure (resubmit — R2 bench was an infra failure):
//  * 32 Q-rows per wave (2 i-subtiles) -> 128-row Q-tile per block. kf/vf
//    LDS fragments shared across the 2 subtiles: 40 b128 reads / 72 MFMA
//    per wave-iter (was 72/72 per unit work). Staging bytes/work halved.
//  * K/V + cum DOUBLE-BUFFERED; prefetch for iter g+1 issued right after
//    the (single) barrier of iter g via global_load_lds -> the vmcnt drain
//    at the next barrier is free. ONE __syncthreads per iteration.
//  * cum windows: phase stride 264 f32 (== 8 mod 32 banks). Old stride 192
//    aligned all 4 phase arrays on the same banks -> 2x conflict on every
//    bias read = the 5.01M SQ_LDS_BANK_CONFLICT. 264 spreads phases.
//  * grid 256 = 1 block/CU, pair {15-pr, pr} = exactly 17 iters per block,
//    perfect balance. 4 waves/CU: phase drift among waves feeds the DS pipe.
// q,k: [bn][S][D] bf16;  vt: [bn][D][S] bf16;  cum: [N][S] f32 (xLOG2E);
// mix out: [b][s][n][d] bf16
// LDS: K/V dbuf [0,65536) (buf b at b*32768: K 16K then V 16K);
//      Ps[128][136] [65536,100352); cum [2][4][264] f32 [100352,108800).
// ---------------------------------------------------------------------------
__device__ __forceinline__ void fa_stage(const bf16* __restrict__ k,
                                         const bf16* __restrict__ vt,
                                         const float* __restrict__ cumn,
                                         char* smem, int bn, int i0p, int j0p,
                                         int buf, int lane, int w, int tid) {
  char* dst = smem + buf * 32768;
  // K tile: rows j0p..j0p+127, swizzled (slot (row,c) holds chunk c^(row&7))
  const char* ksrc = (const char*)(k + ((size_t)bn * S_ + j0p) * DH);
#pragma unroll
  for (int t = 0; t < 4; ++t) {
    int cb = t * 4 + w;
    int row = cb * 8 + (lane >> 3);
    int cs = (lane & 7) ^ (row & 7);
    async16(ksrc + row * 128 + cs * 16, dst + cb * 1024 + lane * 16);
  }
  // Vt tile: d rows 0..63, cols j0p..j0p+127 (slot (d,c) holds c^(d&15))
  const char* vsrc = (const char*)(vt + (size_t)bn * DH * S_);
#pragma unroll
  for (int t = 0; t < 4; ++t) {
    int cb = t * 4 + w;
    int row = cb * 4 + (lane >> 4);          // d index 0..63
    int cs = (lane & 15) ^ (row & 15);
    async16(vsrc + (size_t)row * (S_ * 2) + j0p * 2 + cs * 16,
            dst + 16384 + cb * 1024 + lane * 16);
  }
  // cum windows: cumS[buf][p][t] = cumn[clamp(i0p - j0p - 127 + t + p)],
  // t = tid (0..255). async4: wave-uniform LDS base + lane*4.
  float* cdst = (float*)(smem + 100352) + buf * 1056;  // 4*264
  int base = i0p - j0p - 127 + tid;
#pragma unroll
  for (int p = 0; p < 4; ++p) {
    int src = base + p;
    src = src < 0 ? 0 : (src > S_ - 1 ? S_ - 1 : src);
    async4(cumn + src, cdst + p * 264 + w * 64 + lane);
  }
}

__global__ __launch_bounds__(256, 1)
void fa_kernel(const bf16* __restrict__ q, const bf16* __restrict__ k,
               const bf16* __restrict__ vt, const float* __restrict__ cum,
               bf16* __restrict__ mix) {
  __shared__ char smem[108800] __attribute__((aligned(16)));
  bf16* Ps = (bf16*)(smem + 65536);             // [128][136]

  const int tid = threadIdx.x, lane = tid & 63, w = tid >> 6;  // w: 0..3
  const int lr = lane & 15, lq = lane >> 4;

  const int L = blockIdx.x;                     // 0..255
  const int xcd = L & 7, slot = L >> 3;         // slot 0..31
  const int bn = xcd + 8 * (slot & 3);          // 4 heads per XCD
  const int pr = slot >> 2;                     // pair index 0..7
  const int n = bn & (NH - 1);
  const int b = bn >> 4;
  const float* cumn = cum + n * S_;

  const int T0 = 15 - pr;                       // heavy tile (cost 16-pr)
  const int T1 = pr;                            // light tile (cost pr+1)
  const int nj0 = T0 + 1;

  // all-ones B fragment for the l row-sum MFMA
  bf16x8 ones;
#pragma unroll
  for (int u = 0; u < 8; ++u) ones[u] = (short)0x3F80;
  const f32x4 fz = {0.f, 0.f, 0.f, 0.f};

  // prologue: stage iter 0 (tile T0, jt 0) into buf 0
  fa_stage(k, vt, cumn, smem, bn, T0 << 7, 0, 0, lane, w, tid);

  f32x4 oacc[2][4];
  f32x4 lacc[2];
  bf16x8 qf[2][2];
  int ti = T0, jt = 0, i0 = T0 << 7;

  for (int g = 0; g < 17; ++g) {
    const int bsel = g & 1;
    const char* kb = smem + bsel * 32768;
    const char* vb = kb + 16384;
    const float* cumB = (const float*)(smem + 100352) + bsel * 1056;
    const bool diag = (jt == ti);               // last iter of this phase

    __syncthreads();   // staged data for g visible; buf^1 prior reads done

    // prefetch iter g+1 into the other buffer (flies during this compute)
    if (g + 1 < 17) {
      int gn = g + 1, tin, jtn;
      if (gn < nj0) { tin = T0; jtn = gn; }
      else          { tin = T1; jtn = gn - nj0; }
      fa_stage(k, vt, cumn, smem, bn, tin << 7, jtn << 7, bsel ^ 1, lane, w, tid);
    }

    if (jt == 0) {
      // new phase: load Q fragments (B-operand for S^T = K*Q^T), reset acc
      const bf16* qbase = q + ((size_t)bn * S_ + i0 + w * 32) * DH;
#pragma unroll
      for (int is = 0; is < 2; ++is)
#pragma unroll
        for (int kt = 0; kt < 2; ++kt)
          qf[is][kt] = *(const bf16x8*)(qbase + (is * 16 + lr) * DH + kt * 32 + lq * 8);
#pragma unroll
      for (int is = 0; is < 2; ++is) {
        lacc[is] = fz;
#pragma unroll
        for (int dt = 0; dt < 4; ++dt) oacc[is][dt] = fz;
      }
    }

    // S^T = K * Q^T; kf shared across the 2 i-subtiles.
    // sa[is][nt][r] = S[i = i0 + w*32 + is*16 + lr][j = j0 + nt*16 + lq*4 + r]
    f32x4 sa[2][8] = {};
#pragma unroll
    for (int kt = 0; kt < 2; ++kt)
#pragma unroll
      for (int nt = 0; nt < 8; ++nt) {
        int krow = nt * 16 + lr;
        bf16x8 kf = *(const bf16x8*)(kb + krow * 128 +
                        (((kt * 4 + lq) ^ (krow & 7)) << 4));
        sa[0][nt] = MFMA16(kf, qf[0][kt], sa[0][nt]);
        sa[1][nt] = MFMA16(kf, qf[1][kt], sa[1][nt]);
      }

    // p = exp2(s*SCALE2 + cum[i-j]) (no max subtraction), pack, write P.
    // One b128 bias read per reg-quad: Xm3 in [0,251], cv[m]=win[Xm3+m],
    // bias(r) = cv[3-r]. Phase stride 264 breaks the old bank alignment.
#pragma unroll
    for (int is = 0; is < 2; ++is) {
      const int ilocI = w * 32 + is * 16 + lr;  // 0..127
      if (!diag) {
#pragma unroll
        for (int nt = 0; nt < 8; ++nt) {
          int jl = nt * 16 + lq * 4;
          int Xm3 = 124 + ilocI - jl;
          int p = Xm3 & 3, b0 = Xm3 & ~3;
          f32x4 cv = *(const f32x4*)(cumB + p * 264 + b0);
          bf16 pk[4];
#pragma unroll
          for (int r = 0; r < 4; ++r)
            pk[r] = __float2bfloat16(exp2f(sa[is][nt][r] * SCALE2 + cv[3 - r]));
          *(uint64_t*)(Ps + ilocI * 136 + nt * 16 + lq * 4) = *(const uint64_t*)pk;
        }
      } else {
#pragma unroll
        for (int nt = 0; nt < 8; ++nt) {
          int jl = nt * 16 + lq * 4;
          int Xm3 = 124 + ilocI - jl;
          int p = Xm3 & 3, b0 = Xm3 & ~3;
          f32x4 cv = *(const f32x4*)(cumB + p * 264 + b0);
          bf16 pk[4];
#pragma unroll
          for (int r = 0; r < 4; ++r) {
            float pv = (ilocI - jl - r >= 0)       // i0 == j0 on diagonal tile
                           ? exp2f(sa[is][nt][r] * SCALE2 + cv[3 - r])
                           : 0.f;
            pk[r] = __float2bfloat16(pv);
          }
          *(uint64_t*)(Ps + ilocI * 136 + nt * 16 + lq * 4) = *(const uint64_t*)pk;
        }
      }
    }

    // O += P V; l += P 1. vf shared across the 2 i-subtiles.
    // (wave-private P rows; in-wave DS ordering suffices)
#pragma unroll
    for (int kt2 = 0; kt2 < 4; ++kt2) {
      bf16x8 pf0 = *(const bf16x8*)(Ps + (w * 32 + lr) * 136 + kt2 * 32 + lq * 8);
      bf16x8 pf1 = *(const bf16x8*)(Ps + (w * 32 + 16 + lr) * 136 + kt2 * 32 + lq * 8);
      lacc[0] = MFMA16(pf0, ones, lacc[0]);
      lacc[1] = MFMA16(pf1, ones, lacc[1]);
#pragma unroll
      for (int dt = 0; dt < 4; ++dt) {
        int vrow = dt * 16 + lr;
        bf16x8 vf = *(const bf16x8*)(vb + vrow * 256 +
                        (((kt2 * 4 + lq) ^ (vrow & 15)) << 4));
        oacc[0][dt] = MFMA16(pf0, vf, oacc[0][dt]);
        oacc[1][dt] = MFMA16(pf1, vf, oacc[1][dt]);
      }
    }

    if (diag) {
      // phase epilogue: mix[b][s][n][d]; lacc[is][r] = row sum for its row
#pragma unroll
      for (int is = 0; is < 2; ++is)
#pragma unroll
        for (int dt = 0; dt < 4; ++dt)
#pragma unroll
          for (int r = 0; r < 4; ++r) {
            int i = i0 + w * 32 + is * 16 + lq * 4 + r;
            int d = dt * 16 + lr;
            mix[((size_t)(b * S_ + i) * NH + n) * DH + d] =
                __float2bfloat16(oacc[is][dt][r] / lacc[is][r]);
          }
      ti = T1; jt = 0; i0 = T1 << 7;            // switch to light phase
    } else {
      ++jt;
    }
  }
}

// ---------------------------------------------------------------------------
extern "C" void kernel_launch(void* const* d_in, const int* in_sizes, int n_in,
                              void* d_out, int out_size, void* d_ws, size_t ws_size,
                              hipStream_t stream) {
  const float* x     = (const float*)d_in[0];   // [B,S,H] f32
  const float* qkv   = (const float*)d_in[1];   // [H,3,N,D] f32 == [1024][3072]
  const float* out_w = (const float*)d_in[2];   // [N,D,H] f32   == [1024][1024]
  const float* rpe   = (const float*)d_in[3];   // [N,S] f32
  float* out = (float*)d_out;                   // [B,S,H] f32

  char* ws = (char*)d_ws;
  bf16* qkvT  = (bf16*)(ws + 0);          // [3072][1024] bf16   6291456 B
  bf16* outwT = (bf16*)(ws + 6291456);    // [1024][1024] bf16   2097152 B
  bf16* xb    = (bf16*)(ws + 8388608);    // [4096][1024] bf16   8388608 B
  bf16* qb    = (bf16*)(ws + 16777216);   // [bn][S][D]          8388608 B
  bf16* kb    = (bf16*)(ws + 25165824);   // [bn][S][D]          8388608 B
  bf16* vtb   = (bf16*)(ws + 33554432);   // [bn][D][S]          8388608 B
  bf16* mixb  = (bf16*)(ws + 41943040);   // [b][s][n][d]        8388608 B
  float* cum  = (float*)(ws + 50331648);  // [N][S] f32 (xLOG2E)  131072 B

  // 1. fused prep: convert x, transpose+convert weights, rpe cumsum
  prep<<<8208, 256, 0, stream>>>(x, xb, qkv, qkvT, out_w, outwT, rpe, cum);
  // 2. QKV projection (V written pre-transposed; 768 blocks = 3/CU, no tail)
  gemm_bt<0><<<dim3(3072 / 128, 4096 / 128), 256, 0, stream>>>(xb, qkvT, qb, kb, vtb, nullptr);
  // 3. attention: 256 blocks (1/CU), 128-row Q-tiles, double-buffered K/V,
  //    paired {15-pr, pr} = exactly 17 KV-iters per block
  fa_kernel<<<256, 256, 0, stream>>>(qb, kb, vtb, cum, mixb);
  // 4. output projection (f32 out; 128x64 tiles -> 512 blocks = 2/CU)
  gemm_bt<1><<<dim3(1024 / 64, 4096 / 128), 256, 0, stream>>>(mixb, outwT, nullptr, nullptr, nullptr, out);
}

// Round 4
// 193.984 us; speedup vs baseline: 1.0600x; 1.0600x over previous
//
#include <hip/hip_runtime.h>
#include <hip/hip_bf16.h>
#include <cstdint>
#include <cstddef>

// Problem constants
#define B_   2
#define S_   2048
#define H_   1024
#define NH   16
#define DH   64
#define LOG2E 1.4426950408889634f
#define SCALE2 (0.125f * LOG2E)   // D^-0.5 * log2(e): softmax done in exp2 domain

typedef __hip_bfloat16 bf16;
typedef short bf16x8 __attribute__((ext_vector_type(8)));   // 8 bf16 in 4 VGPRs
typedef float f32x4 __attribute__((ext_vector_type(4)));

#define MFMA16(a, b, c) __builtin_amdgcn_mfma_f32_16x16x32_bf16((a), (b), (c), 0, 0, 0)

__device__ __forceinline__ void async16(const void* g, void* l) {
  __builtin_amdgcn_global_load_lds(
      (const __attribute__((address_space(1))) void*)g,
      (__attribute__((address_space(3))) void*)l,
      16, 0, 0);
}
__device__ __forceinline__ void async4(const void* g, void* l) {
  __builtin_amdgcn_global_load_lds(
      (const __attribute__((address_space(1))) void*)g,
      (__attribute__((address_space(3))) void*)l,
      4, 0, 0);
}

// ---------------------------------------------------------------------------
// Fused prep kernel (one dispatch, grid 8208) — unchanged.
// ---------------------------------------------------------------------------
__device__ __forceinline__ void tr_body(const float* __restrict__ src,
                                        bf16* __restrict__ dst, int R, int C,
                                        int c0, int r0, bf16 (*tile)[33], int tid) {
  int tx = tid & 31, ty = tid >> 5;   // 32 x 8
  for (int i = 0; i < 32; i += 8)
    tile[ty + i][tx] = __float2bfloat16(src[(size_t)(r0 + ty + i) * C + c0 + tx]);
  __syncthreads();
  for (int i = 0; i < 32; i += 8)
    dst[(size_t)(c0 + ty + i) * R + r0 + tx] = tile[tx][ty + i];
}

__global__ __launch_bounds__(256)
void prep(const float* __restrict__ x, bf16* __restrict__ xb,
          const float* __restrict__ qkv, bf16* __restrict__ qkvT,
          const float* __restrict__ outw, bf16* __restrict__ outwT,
          const float* __restrict__ rpe, float* __restrict__ cum) {
  __shared__ char pm[2176] __attribute__((aligned(16)));
  const int L = blockIdx.x, tid = threadIdx.x;
  if (L < 4096) {
    int i = (L * 256 + tid) * 4;
    float4 v = *(const float4*)(x + i);
    bf16 o[4] = {__float2bfloat16(v.x), __float2bfloat16(v.y),
                 __float2bfloat16(v.z), __float2bfloat16(v.w)};
    *(uint64_t*)(xb + i) = *(const uint64_t*)o;
  } else if (L < 7168) {
    int t = L - 4096;
    int cx = t % 96, ry = t / 96;
    tr_body(qkv, qkvT, 1024, 3072, cx * 32, ry * 32, (bf16(*)[33])pm, tid);
  } else if (L < 8192) {
    int t = L - 7168;
    int cx = t & 31, ry = t >> 5;
    tr_body(outw, outwT, 1024, 1024, cx * 32, ry * 32, (bf16(*)[33])pm, tid);
  } else {
    // rpe cumsum (scaled by LOG2E)
    float* ssum = (float*)pm;
    int n = L - 8192;
    float loc[8];
    float s = 0.f;
    int base = tid * 8;
#pragma unroll
    for (int u = 0; u < 8; ++u) {
      loc[u] = rpe[n * S_ + base + u];
      s += loc[u];
    }
    ssum[tid] = s;
    __syncthreads();
    float own = s;
    for (int off = 1; off < 256; off <<= 1) {
      float v = (tid >= off) ? ssum[tid - off] : 0.f;
      __syncthreads();
      ssum[tid] += v;
      __syncthreads();
    }
    float run = ssum[tid] - own;   // exclusive prefix of this thread's chunk
#pragma unroll
    for (int u = 0; u < 8; ++u) {
      run += loc[u];
      cum[n * S_ + base + u] = run * LOG2E;
    }
  }
}

// ---------------------------------------------------------------------------
// GEMM — unchanged.
// ---------------------------------------------------------------------------
template <int MODE>
__global__ __launch_bounds__(256, MODE == 0 ? 3 : 2)
void gemm_bt(const bf16* __restrict__ A, const bf16* __restrict__ Bt,
             bf16* __restrict__ C0, bf16* __restrict__ C1, bf16* __restrict__ C2,
             float* __restrict__ F0) {
  constexpr int NT = (MODE == 0) ? 4 : 2;     // n-subtiles per wave
  constexpr int NB = NT * 32;                 // block n-extent: 128 or 64
  __shared__ char smem[MODE == 0 ? 36864 : 12288] __attribute__((aligned(16)));
  bf16* As = (bf16*)smem;              // [128*32]
  bf16* Bs = (bf16*)(smem + 8192);     // [NB*32]
  const int tid = threadIdx.x, lane = tid & 63, w = tid >> 6;
  const int lr = lane & 15, lq = lane >> 4;
  const int m0 = blockIdx.y * 128, n0 = blockIdx.x * NB;
  const int wm = (w & 1) * 64, wn = (w >> 1) * (NT * 16);

  f32x4 acc[4][NT] = {};

  for (int k0 = 0; k0 < 1024; k0 += 32) {
    __syncthreads();
#pragma unroll
    for (int t = 0; t < 2; ++t) {
      int c = (t * 4 + w) * 64 + lane;          // 16B-chunk id 0..511
      int row = c >> 2, ch = c & 3;
      int k8 = (ch ^ ((row >> 1) & 3)) * 8;     // swizzled source chunk
      async16(A + (size_t)(m0 + row) * 1024 + k0 + k8,
              (char*)As + (size_t)(t * 4 + w) * 1024 + lane * 16);
    }
#pragma unroll
    for (int t = 0; t < NB / 64; ++t) {
      int c = (t * 4 + w) * 64 + lane;          // chunk id, NB*4 total
      int row = c >> 2, ch = c & 3;
      int k8 = (ch ^ ((row >> 1) & 3)) * 8;
      async16(Bt + (size_t)(n0 + row) * 1024 + k0 + k8,
              (char*)Bs + (size_t)(t * 4 + w) * 1024 + lane * 16);
    }
    __syncthreads();
    bf16x8 af[4], bfr[NT];
#pragma unroll
    for (int mt = 0; mt < 4; ++mt) {
      int row = wm + mt * 16 + lr;
      af[mt] = *(const bf16x8*)(As + row * 32 + ((lq ^ ((row >> 1) & 3)) << 3));
    }
#pragma unroll
    for (int nt = 0; nt < NT; ++nt) {
      int row = wn + nt * 16 + lr;
      bfr[nt] = *(const bf16x8*)(Bs + row * 32 + ((lq ^ ((row >> 1) & 3)) << 3));
    }
#pragma unroll
    for (int mt = 0; mt < 4; ++mt)
#pragma unroll
      for (int nt = 0; nt < NT; ++nt)
        acc[mt][nt] = MFMA16(af[mt], bfr[nt], acc[mt][nt]);
  }

  if (MODE == 0) {
    __syncthreads();   // all As/Bs reads done; reuse LDS for epilogue tiles
    bf16* E = (bf16*)smem + w * (64 * 72);   // wave-private [64][72]
    const int cbase = n0 + wn;               // 64-aligned
    const int mm = cbase >> 10, nn = (cbase >> 6) & 15;
    const int bb = (m0 + wm) >> 11;
    const int sbase = (m0 + wm) & 2047;
    if (mm < 2) {
      // write acc as [s][d] into E
#pragma unroll
      for (int mt = 0; mt < 4; ++mt)
#pragma unroll
        for (int nt = 0; nt < 4; ++nt)
#pragma unroll
          for (int r = 0; r < 4; ++r)
            E[(mt * 16 + lq * 4 + r) * 72 + nt * 16 + lr] =
                __float2bfloat16(acc[mt][nt][r]);
      // wave-private readback (in-wave lgkm ordering), b128 stores
      bf16* dst = (mm == 0 ? C0 : C1) +
                  ((size_t)(bb * NH + nn) * S_ + sbase) * DH;
#pragma unroll
      for (int it = 0; it < 8; ++it) {
        int c = it * 64 + lane;
        int rw = c >> 3, c8 = c & 7;
        *(uint4*)(dst + (size_t)rw * DH + c8 * 8) =
            *(const uint4*)(E + rw * 72 + c8 * 8);
      }
    } else {
      // V: write acc as [d][s] into E
#pragma unroll
      for (int mt = 0; mt < 4; ++mt)
#pragma unroll
        for (int nt = 0; nt < 4; ++nt)
#pragma unroll
          for (int r = 0; r < 4; ++r)
            E[(nt * 16 + lr) * 72 + mt * 16 + lq * 4 + r] =
                __float2bfloat16(acc[mt][nt][r]);
      bf16* dst = C2 + (size_t)(bb * NH + nn) * DH * S_;
#pragma unroll
      for (int it = 0; it < 8; ++it) {
        int c = it * 64 + lane;
        int dr = c >> 3, c8 = c & 7;
        *(uint4*)(dst + (size_t)dr * S_ + sbase + c8 * 8) =
            *(const uint4*)(E + dr * 72 + c8 * 8);
      }
    }
  } else {
#pragma unroll
    for (int mt = 0; mt < 4; ++mt)
#pragma unroll
      for (int nt = 0; nt < NT; ++nt)
#pragma unroll
        for (int r = 0; r < 4; ++r) {
          int rM = m0 + wm + mt * 16 + lq * 4 + r;
          int cN = n0 + wn + nt * 16 + lr;
          F0[(size_t)rM * 1024 + cN] = acc[mt][nt][r];
        }
  }
}

// ---------------------------------------------------------------------------
// Flash attention, R4: R3 structure (32 Q-rows/wave kf/vf sharing, dbuf +
// prefetch, single barrier/iter, phase-shifted cum windows) but restored to
// 2 BLOCKS/CU — R3's regression was 1 wave/SIMD (OccupancyPercent 10.6):
// all ds_read/MFMA latency exposed, zero wave overlap.
//  * KV tile halved to 64 cols -> LDS/block 59.6 KB -> 2 blocks/CU.
//  * grid 512: blocks [0,256) take heavy tile 15-pr, [256,512) light tile
//    pr, same (bn,pr) -> HW round-robin co-schedules L and L+256 on one CU
//    (the measured mapping behind the R0->R1 win): per-CU iters =
//    (32-2pr)+(2pr+2) = 36 exactly, 8 waves/CU.
//  * swizzles re-derived for 128B K/V rows (chunk c^(row&7)): 2-way max.
//  * LAST TWO iters of each tile need causal masking (64-col granularity).
// q,k: [bn][S][D] bf16;  vt: [bn][D][S] bf16;  cum: [N][S] f32 (xLOG2E);
// mix out: [b][s][n][d] bf16
// LDS: K/V dbuf [0,32768) (buf b at b*16384: K 8K, V 8K);
//      Ps[128][72] [32768,51200); cum [2][4][264] f32 [51200,59648).
// ---------------------------------------------------------------------------
__device__ __forceinline__ void fa_stage(const bf16* __restrict__ k,
                                         const bf16* __restrict__ vt,
                                         const float* __restrict__ cumn,
                                         char* smem, int bn, int i0, int j0,
                                         int buf, int tid) {
  char* dst = smem + buf * 16384;
  // K tile: rows j0..j0+63 (128B each, 8 chunks); slot (row,ch) holds
  // global chunk ch^(row&7). 512 chunks, 2 per thread.
  const char* ksrc = (const char*)(k + ((size_t)bn * S_ + j0) * DH);
#pragma unroll
  for (int t = 0; t < 2; ++t) {
    int c = t * 256 + tid;                    // 0..511
    int row = c >> 3, ch = c & 7;
    int cs = ch ^ (row & 7);
    async16(ksrc + row * 128 + cs * 16, dst + c * 16);
  }
  // Vt tile: d rows 0..63, cols j0..j0+63 (128B each); slot (d,ch) holds
  // global chunk ch^(d&7).
  const char* vsrc = (const char*)(vt + (size_t)bn * DH * S_);
#pragma unroll
  for (int t = 0; t < 2; ++t) {
    int c = t * 256 + tid;
    int row = c >> 3, ch = c & 7;             // row = d index
    int cs = ch ^ (row & 7);
    async16(vsrc + (size_t)row * (S_ * 2) + j0 * 2 + cs * 16,
            dst + 8192 + c * 16);
  }
  // cum windows: cumS[buf][p][t] = cumn[clamp(i0-j0-63 + t + p)], t=tid.
  // Stride 264 words == 8 mod 32 banks. Reads only touch t <= 187.
  float* cdst = (float*)(smem + 51200) + buf * 1056;  // 4*264
  int base = i0 - j0 - 63 + tid;
#pragma unroll
  for (int p = 0; p < 4; ++p) {
    int src = base + p;
    src = src < 0 ? 0 : (src > S_ - 1 ? S_ - 1 : src);
    async4(cumn + src, cdst + p * 264 + tid);
  }
}

__global__ __launch_bounds__(256, 2)
void fa_kernel(const bf16* __restrict__ q, const bf16* __restrict__ k,
               const bf16* __restrict__ vt, const float* __restrict__ cum,
               bf16* __restrict__ mix) {
  __shared__ char smem[59648] __attribute__((aligned(16)));
  bf16* Ps = (bf16*)(smem + 32768);             // [128][72]

  const int tid = threadIdx.x, lane = tid & 63, w = tid >> 6;  // w: 0..3
  const int lr = lane & 15, lq = lane >> 4;

  const int L = blockIdx.x;                     // 0..511
  const int half = L >> 8;                      // 0 = heavy, 1 = light
  const int idx = L & 255;
  const int xcd = idx & 7, slot = idx >> 3;     // slot 0..31
  const int bn = xcd + 8 * (slot & 3);          // 4 heads per XCD
  const int pr = slot >> 2;                     // 0..7
  const int ti = half ? pr : (15 - pr);         // Q-tile id (128 rows)
  const int n = bn & (NH - 1);
  const int b = bn >> 4;
  const float* cumn = cum + n * S_;

  const int i0 = ti << 7;
  const int NI = 2 * ti + 2;                    // 64-col KV iters

  // Q fragments (B-operand for S^T = K*Q^T), loaded once
  const bf16* qbase = q + ((size_t)bn * S_ + i0 + w * 32) * DH;
  bf16x8 qf[2][2];
#pragma unroll
  for (int is = 0; is < 2; ++is)
#pragma unroll
    for (int kt = 0; kt < 2; ++kt)
      qf[is][kt] = *(const bf16x8*)(qbase + (is * 16 + lr) * DH + kt * 32 + lq * 8);

  // all-ones B fragment for the l row-sum MFMA
  bf16x8 ones;
#pragma unroll
  for (int u = 0; u < 8; ++u) ones[u] = (short)0x3F80;

  f32x4 oacc[2][4] = {};
  f32x4 lacc[2] = {};

  // prologue: stage iter 0 into buf 0
  fa_stage(k, vt, cumn, smem, bn, i0, 0, 0, tid);

  for (int g = 0; g < NI; ++g) {
    const int bsel = g & 1;
    const char* kb = smem + bsel * 16384;
    const char* vb = kb + 8192;
    const float* cumB = (const float*)(smem + 51200) + bsel * 1056;
    const int j0 = g << 6;
    const int doff = i0 - j0;                   // >= 64 on non-masked iters

    __syncthreads();   // staged data for g visible; buf^1 prior reads done

    // prefetch iter g+1 into the other buffer (flies during this compute)
    if (g + 1 < NI)
      fa_stage(k, vt, cumn, smem, bn, i0, (g + 1) << 6, bsel ^ 1, tid);

    // S^T = K * Q^T; kf shared across the 2 i-subtiles.
    // sa[is][nt][r] = S[i = i0+w*32+is*16+lr][j = j0 + nt*16 + lq*4 + r]
    f32x4 sa[2][4] = {};
#pragma unroll
    for (int kt = 0; kt < 2; ++kt)
#pragma unroll
      for (int nt = 0; nt < 4; ++nt) {
        int krow = nt * 16 + lr;
        bf16x8 kf = *(const bf16x8*)(kb + krow * 128 +
                        (((kt * 4 + lq) ^ (krow & 7)) << 4));
        sa[0][nt] = MFMA16(kf, qf[0][kt], sa[0][nt]);
        sa[1][nt] = MFMA16(kf, qf[1][kt], sa[1][nt]);
      }

    // p = exp2(s*SCALE2 + cum[i-j]) (no max subtraction), pack, write P.
    // One b128 bias read per reg-quad: Xm3 = 60+ilocI-jl in [0,187],
    // cv[m] = win[Xm3+m], bias(r) = cv[3-r].
#pragma unroll
    for (int is = 0; is < 2; ++is) {
      const int ilocI = w * 32 + is * 16 + lr;  // 0..127
      if (doff >= 64) {
#pragma unroll
        for (int nt = 0; nt < 4; ++nt) {
          int jl = nt * 16 + lq * 4;
          int Xm3 = 60 + ilocI - jl;
          int p = Xm3 & 3, b0 = Xm3 & ~3;
          f32x4 cv = *(const f32x4*)(cumB + p * 264 + b0);
          bf16 pk[4];
#pragma unroll
          for (int r = 0; r < 4; ++r)
            pk[r] = __float2bfloat16(exp2f(sa[is][nt][r] * SCALE2 + cv[3 - r]));
          *(uint64_t*)(Ps + ilocI * 72 + nt * 16 + lq * 4) = *(const uint64_t*)pk;
        }
      } else {
#pragma unroll
        for (int nt = 0; nt < 4; ++nt) {
          int jl = nt * 16 + lq * 4;
          int Xm3 = 60 + ilocI - jl;
          int p = Xm3 & 3, b0 = Xm3 & ~3;
          f32x4 cv = *(const f32x4*)(cumB + p * 264 + b0);
          bf16 pk[4];
#pragma unroll
          for (int r = 0; r < 4; ++r) {
            float pv = (doff + ilocI - jl - r >= 0)
                           ? exp2f(sa[is][nt][r] * SCALE2 + cv[3 - r])
                           : 0.f;
            pk[r] = __float2bfloat16(pv);
          }
          *(uint64_t*)(Ps + ilocI * 72 + nt * 16 + lq * 4) = *(const uint64_t*)pk;
        }
      }
    }

    // O += P V; l += P 1. vf shared across the 2 i-subtiles.
    // (wave-private P rows; in-wave DS ordering suffices)
#pragma unroll
    for (int kt2 = 0; kt2 < 2; ++kt2) {
      bf16x8 pf0 = *(const bf16x8*)(Ps + (w * 32 + lr) * 72 + kt2 * 32 + lq * 8);
      bf16x8 pf1 = *(const bf16x8*)(Ps + (w * 32 + 16 + lr) * 72 + kt2 * 32 + lq * 8);
      lacc[0] = MFMA16(pf0, ones, lacc[0]);
      lacc[1] = MFMA16(pf1, ones, lacc[1]);
#pragma unroll
      for (int dt = 0; dt < 4; ++dt) {
        int vrow = dt * 16 + lr;
        bf16x8 vf = *(const bf16x8*)(vb + vrow * 128 +
                        (((kt2 * 4 + lq) ^ (vrow & 7)) << 4));
        oacc[0][dt] = MFMA16(pf0, vf, oacc[0][dt]);
        oacc[1][dt] = MFMA16(pf1, vf, oacc[1][dt]);
      }
    }
  }

  // epilogue: mix[b][s][n][d]; lacc[is][r] is the row sum for its row
#pragma unroll
  for (int is = 0; is < 2; ++is)
#pragma unroll
    for (int dt = 0; dt < 4; ++dt)
#pragma unroll
      for (int r = 0; r < 4; ++r) {
        int i = i0 + w * 32 + is * 16 + lq * 4 + r;
        int d = dt * 16 + lr;
        mix[((size_t)(b * S_ + i) * NH + n) * DH + d] =
            __float2bfloat16(oacc[is][dt][r] / lacc[is][r]);
      }
}

// ---------------------------------------------------------------------------
extern "C" void kernel_launch(void* const* d_in, const int* in_sizes, int n_in,
                              void* d_out, int out_size, void* d_ws, size_t ws_size,
                              hipStream_t stream) {
  const float* x     = (const float*)d_in[0];   // [B,S,H] f32
  const float* qkv   = (const float*)d_in[1];   // [H,3,N,D] f32 == [1024][3072]
  const float* out_w = (const float*)d_in[2];   // [N,D,H] f32   == [1024][1024]
  const float* rpe   = (const float*)d_in[3];   // [N,S] f32
  float* out = (float*)d_out;                   // [B,S,H] f32

  char* ws = (char*)d_ws;
  bf16* qkvT  = (bf16*)(ws + 0);          // [3072][1024] bf16   6291456 B
  bf16* outwT = (bf16*)(ws + 6291456);    // [1024][1024] bf16   2097152 B
  bf16* xb    = (bf16*)(ws + 8388608);    // [4096][1024] bf16   8388608 B
  bf16* qb    = (bf16*)(ws + 16777216);   // [bn][S][D]          8388608 B
  bf16* kb    = (bf16*)(ws + 25165824);   // [bn][S][D]          8388608 B
  bf16* vtb   = (bf16*)(ws + 33554432);   // [bn][D][S]          8388608 B
  bf16* mixb  = (bf16*)(ws + 41943040);   // [b][s][n][d]        8388608 B
  float* cum  = (float*)(ws + 50331648);  // [N][S] f32 (xLOG2E)  131072 B

  // 1. fused prep: convert x, transpose+convert weights, rpe cumsum
  prep<<<8208, 256, 0, stream>>>(x, xb, qkv, qkvT, out_w, outwT, rpe, cum);
  // 2. QKV projection (V written pre-transposed; 768 blocks = 3/CU, no tail)
  gemm_bt<0><<<dim3(3072 / 128, 4096 / 128), 256, 0, stream>>>(xb, qkvT, qb, kb, vtb, nullptr);
  // 3. attention: 512 blocks = 2/CU (heavy half [0,256) + light half
  //    [256,512) co-resident), 128-row Q-tiles, 64-col KV iters, dbuf
  fa_kernel<<<512, 256, 0, stream>>>(qb, kb, vtb, cum, mixb);
  // 4. output projection (f32 out; 128x64 tiles -> 512 blocks = 2/CU)
  gemm_bt<1><<<dim3(1024 / 64, 4096 / 128), 256, 0, stream>>>(mixb, outwT, nullptr, nullptr, nullptr, out);
}

// Round 5
// 184.820 us; speedup vs baseline: 1.1125x; 1.0496x over previous
//
#include <hip/hip_runtime.h>
#include <hip/hip_bf16.h>
#include <cstdint>
#include <cstddef>

// Problem constants
#define B_   2
#define S_   2048
#define H_   1024
#define NH   16
#define DH   64
#define LOG2E 1.4426950408889634f
#define SCALE2 (0.125f * LOG2E)   // D^-0.5 * log2(e): softmax done in exp2 domain

typedef __hip_bfloat16 bf16;
typedef short bf16x8 __attribute__((ext_vector_type(8)));   // 8 bf16 in 4 VGPRs
typedef float f32x4 __attribute__((ext_vector_type(4)));

#define MFMA16(a, b, c) __builtin_amdgcn_mfma_f32_16x16x32_bf16((a), (b), (c), 0, 0, 0)

__device__ __forceinline__ void async16(const void* g, void* l) {
  __builtin_amdgcn_global_load_lds(
      (const __attribute__((address_space(1))) void*)g,
      (__attribute__((address_space(3))) void*)l,
      16, 0, 0);
}
__device__ __forceinline__ void async4(const void* g, void* l) {
  __builtin_amdgcn_global_load_lds(
      (const __attribute__((address_space(1))) void*)g,
      (__attribute__((address_space(3))) void*)l,
      4, 0, 0);
}

// ---------------------------------------------------------------------------
// Fused prep kernel (one dispatch, grid 8208) — unchanged.
// ---------------------------------------------------------------------------
__device__ __forceinline__ void tr_body(const float* __restrict__ src,
                                        bf16* __restrict__ dst, int R, int C,
                                        int c0, int r0, bf16 (*tile)[33], int tid) {
  int tx = tid & 31, ty = tid >> 5;   // 32 x 8
  for (int i = 0; i < 32; i += 8)
    tile[ty + i][tx] = __float2bfloat16(src[(size_t)(r0 + ty + i) * C + c0 + tx]);
  __syncthreads();
  for (int i = 0; i < 32; i += 8)
    dst[(size_t)(c0 + ty + i) * R + r0 + tx] = tile[tx][ty + i];
}

__global__ __launch_bounds__(256)
void prep(const float* __restrict__ x, bf16* __restrict__ xb,
          const float* __restrict__ qkv, bf16* __restrict__ qkvT,
          const float* __restrict__ outw, bf16* __restrict__ outwT,
          const float* __restrict__ rpe, float* __restrict__ cum) {
  __shared__ char pm[2176] __attribute__((aligned(16)));
  const int L = blockIdx.x, tid = threadIdx.x;
  if (L < 4096) {
    int i = (L * 256 + tid) * 4;
    float4 v = *(const float4*)(x + i);
    bf16 o[4] = {__float2bfloat16(v.x), __float2bfloat16(v.y),
                 __float2bfloat16(v.z), __float2bfloat16(v.w)};
    *(uint64_t*)(xb + i) = *(const uint64_t*)o;
  } else if (L < 7168) {
    int t = L - 4096;
    int cx = t % 96, ry = t / 96;
    tr_body(qkv, qkvT, 1024, 3072, cx * 32, ry * 32, (bf16(*)[33])pm, tid);
  } else if (L < 8192) {
    int t = L - 7168;
    int cx = t & 31, ry = t >> 5;
    tr_body(outw, outwT, 1024, 1024, cx * 32, ry * 32, (bf16(*)[33])pm, tid);
  } else {
    // rpe cumsum (scaled by LOG2E)
    float* ssum = (float*)pm;
    int n = L - 8192;
    float loc[8];
    float s = 0.f;
    int base = tid * 8;
#pragma unroll
    for (int u = 0; u < 8; ++u) {
      loc[u] = rpe[n * S_ + base + u];
      s += loc[u];
    }
    ssum[tid] = s;
    __syncthreads();
    float own = s;
    for (int off = 1; off < 256; off <<= 1) {
      float v = (tid >= off) ? ssum[tid - off] : 0.f;
      __syncthreads();
      ssum[tid] += v;
      __syncthreads();
    }
    float run = ssum[tid] - own;   // exclusive prefix of this thread's chunk
#pragma unroll
    for (int u = 0; u < 8; ++u) {
      run += loc[u];
      cum[n * S_ + base + u] = run * LOG2E;
    }
  }
}

// ---------------------------------------------------------------------------
// GEMM — unchanged.
// ---------------------------------------------------------------------------
template <int MODE>
__global__ __launch_bounds__(256, MODE == 0 ? 3 : 2)
void gemm_bt(const bf16* __restrict__ A, const bf16* __restrict__ Bt,
             bf16* __restrict__ C0, bf16* __restrict__ C1, bf16* __restrict__ C2,
             float* __restrict__ F0) {
  constexpr int NT = (MODE == 0) ? 4 : 2;     // n-subtiles per wave
  constexpr int NB = NT * 32;                 // block n-extent: 128 or 64
  __shared__ char smem[MODE == 0 ? 36864 : 12288] __attribute__((aligned(16)));
  bf16* As = (bf16*)smem;              // [128*32]
  bf16* Bs = (bf16*)(smem + 8192);     // [NB*32]
  const int tid = threadIdx.x, lane = tid & 63, w = tid >> 6;
  const int lr = lane & 15, lq = lane >> 4;
  const int m0 = blockIdx.y * 128, n0 = blockIdx.x * NB;
  const int wm = (w & 1) * 64, wn = (w >> 1) * (NT * 16);

  f32x4 acc[4][NT] = {};

  for (int k0 = 0; k0 < 1024; k0 += 32) {
    __syncthreads();
#pragma unroll
    for (int t = 0; t < 2; ++t) {
      int c = (t * 4 + w) * 64 + lane;          // 16B-chunk id 0..511
      int row = c >> 2, ch = c & 3;
      int k8 = (ch ^ ((row >> 1) & 3)) * 8;     // swizzled source chunk
      async16(A + (size_t)(m0 + row) * 1024 + k0 + k8,
              (char*)As + (size_t)(t * 4 + w) * 1024 + lane * 16);
    }
#pragma unroll
    for (int t = 0; t < NB / 64; ++t) {
      int c = (t * 4 + w) * 64 + lane;          // chunk id, NB*4 total
      int row = c >> 2, ch = c & 3;
      int k8 = (ch ^ ((row >> 1) & 3)) * 8;
      async16(Bt + (size_t)(n0 + row) * 1024 + k0 + k8,
              (char*)Bs + (size_t)(t * 4 + w) * 1024 + lane * 16);
    }
    __syncthreads();
    bf16x8 af[4], bfr[NT];
#pragma unroll
    for (int mt = 0; mt < 4; ++mt) {
      int row = wm + mt * 16 + lr;
      af[mt] = *(const bf16x8*)(As + row * 32 + ((lq ^ ((row >> 1) & 3)) << 3));
    }
#pragma unroll
    for (int nt = 0; nt < NT; ++nt) {
      int row = wn + nt * 16 + lr;
      bfr[nt] = *(const bf16x8*)(Bs + row * 32 + ((lq ^ ((row >> 1) & 3)) << 3));
    }
#pragma unroll
    for (int mt = 0; mt < 4; ++mt)
#pragma unroll
      for (int nt = 0; nt < NT; ++nt)
        acc[mt][nt] = MFMA16(af[mt], bfr[nt], acc[mt][nt]);
  }

  if (MODE == 0) {
    __syncthreads();   // all As/Bs reads done; reuse LDS for epilogue tiles
    bf16* E = (bf16*)smem + w * (64 * 72);   // wave-private [64][72]
    const int cbase = n0 + wn;               // 64-aligned
    const int mm = cbase >> 10, nn = (cbase >> 6) & 15;
    const int bb = (m0 + wm) >> 11;
    const int sbase = (m0 + wm) & 2047;
    if (mm < 2) {
      // write acc as [s][d] into E
#pragma unroll
      for (int mt = 0; mt < 4; ++mt)
#pragma unroll
        for (int nt = 0; nt < 4; ++nt)
#pragma unroll
          for (int r = 0; r < 4; ++r)
            E[(mt * 16 + lq * 4 + r) * 72 + nt * 16 + lr] =
                __float2bfloat16(acc[mt][nt][r]);
      // wave-private readback (in-wave lgkm ordering), b128 stores
      bf16* dst = (mm == 0 ? C0 : C1) +
                  ((size_t)(bb * NH + nn) * S_ + sbase) * DH;
#pragma unroll
      for (int it = 0; it < 8; ++it) {
        int c = it * 64 + lane;
        int rw = c >> 3, c8 = c & 7;
        *(uint4*)(dst + (size_t)rw * DH + c8 * 8) =
            *(const uint4*)(E + rw * 72 + c8 * 8);
      }
    } else {
      // V: write acc as [d][s] into E
#pragma unroll
      for (int mt = 0; mt < 4; ++mt)
#pragma unroll
        for (int nt = 0; nt < 4; ++nt)
#pragma unroll
          for (int r = 0; r < 4; ++r)
            E[(nt * 16 + lr) * 72 + mt * 16 + lq * 4 + r] =
                __float2bfloat16(acc[mt][nt][r]);
      bf16* dst = C2 + (size_t)(bb * NH + nn) * DH * S_;
#pragma unroll
      for (int it = 0; it < 8; ++it) {
        int c = it * 64 + lane;
        int dr = c >> 3, c8 = c & 7;
        *(uint4*)(dst + (size_t)dr * S_ + sbase + c8 * 8) =
            *(const uint4*)(E + dr * 72 + c8 * 8);
      }
    }
  } else {
#pragma unroll
    for (int mt = 0; mt < 4; ++mt)
#pragma unroll
      for (int nt = 0; nt < NT; ++nt)
#pragma unroll
        for (int r = 0; r < 4; ++r) {
          int rM = m0 + wm + mt * 16 + lq * 4 + r;
          int cN = n0 + wn + nt * 16 + lr;
          F0[(size_t)rM * 1024 + cN] = acc[mt][nt][r];
        }
  }
}

// ---------------------------------------------------------------------------
// Flash attention, R5: EQUAL-DURATION blocks + j-split waves.
// R4's failure: heavy/light tiles in SEPARATE blocks -> co-residents have
// unequal duration -> time-avg 4.25 waves/CU (Occupancy 12.8%). Fix: 64-row
// Q-tiles (ti in 0..31, cost ti+1 64-col units), IN-BLOCK pair {31-p, p} =
// exactly 33 units for every p -> 512 blocks, ALL identical duration,
// 2 blocks/CU co-resident for the whole kernel (robust to any HW mapping).
// Waves split j: wave (rg=w&1, jh=w>>1) owns rows rg*32..+32, cols
// jh*32..+32 -> kf/vf amortized over is=2 subtiles (DS reads/unit 56 vs
// R1-equivalent 104). Disjoint-j partial O/l are ADDITIVE (no-max exp2
// softmax) -> per-tile cross-wave combine through the consumed K/V buffer.
// Dbuf + single-barrier prefetch + phase-shifted cum windows retained.
// q,k: [bn][S][D] bf16;  vt: [bn][D][S] bf16;  cum: [N][S] f32 (xLOG2E);
// mix out: [b][s][n][d] bf16
// LDS: K/V dbuf [0,32768) (buf b at b*16384: K 8K, V 8K);
//      Ps[64][72] [32768,41984); cum [2][4][136] f32 [41984,46336);
//      combL[2][32] f32 [46336,46592).  46592*2 per CU = OK.
// ---------------------------------------------------------------------------
__device__ __forceinline__ void fa_stage(const bf16* __restrict__ k,
                                         const bf16* __restrict__ vt,
                                         const float* __restrict__ cumn,
                                         char* smem, int bn, int i0, int j0,
                                         int buf, int tid) {
  char* dst = smem + buf * 16384;
  // K tile: rows j0..j0+63 (128B each, 8 chunks); slot (row,ch) holds
  // global chunk ch^(row&7). 512 chunks, 2 per thread.
  const char* ksrc = (const char*)(k + ((size_t)bn * S_ + j0) * DH);
#pragma unroll
  for (int t = 0; t < 2; ++t) {
    int c = t * 256 + tid;                    // 0..511
    int row = c >> 3, ch = c & 7;
    int cs = ch ^ (row & 7);
    async16(ksrc + row * 128 + cs * 16, dst + c * 16);
  }
  // Vt tile: d rows 0..63, cols j0..j0+63 (128B each); slot (d,ch) holds
  // global chunk ch^(d&7).
  const char* vsrc = (const char*)(vt + (size_t)bn * DH * S_);
#pragma unroll
  for (int t = 0; t < 2; ++t) {
    int c = t * 256 + tid;
    int row = c >> 3, ch = c & 7;             // row = d index
    int cs = ch ^ (row & 7);
    async16(vsrc + (size_t)row * (S_ * 2) + j0 * 2 + cs * 16,
            dst + 8192 + c * 16);
  }
  // cum windows: cumS[buf][p][t] = cumn[clamp(i0-j0-63 + t + p)], t=tid<136.
  // Stride 136 words == 8 mod 32 banks.
  if (tid < 136) {
    float* cdst = (float*)(smem + 41984) + buf * 544;  // 4*136
    int base = i0 - j0 - 63 + tid;
#pragma unroll
    for (int p = 0; p < 4; ++p) {
      int src = base + p;
      src = src < 0 ? 0 : (src > S_ - 1 ? S_ - 1 : src);
      async4(cumn + src, cdst + p * 136 + tid);
    }
  }
}

__global__ __launch_bounds__(256, 2)
void fa_kernel(const bf16* __restrict__ q, const bf16* __restrict__ k,
               const bf16* __restrict__ vt, const float* __restrict__ cum,
               bf16* __restrict__ mix) {
  __shared__ char smem[46592] __attribute__((aligned(16)));
  bf16* Ps = (bf16*)(smem + 32768);             // [64][72]
  float* combL = (float*)(smem + 46336);        // [2][32]

  const int tid = threadIdx.x, lane = tid & 63, w = tid >> 6;  // w: 0..3
  const int lr = lane & 15, lq = lane >> 4;
  const int rg = w & 1, jh = w >> 1;            // row-group, j-half

  const int L = blockIdx.x;                     // 0..511
  const int xcd = L & 7, slot = L >> 3;         // slot 0..63
  const int bn = xcd + 8 * (slot & 3);          // 4 heads per XCD
  const int pp = slot >> 2;                     // pair index 0..15
  const int n = bn & (NH - 1);
  const int b = bn >> 4;
  const float* cumn = cum + n * S_;

  const int T0 = 31 - pp;                       // heavy tile (32-pp units)
  const int T1 = pp;                            // light tile (pp+1 units)
  const int nu0 = T0 + 1;                       // units in tile 0

  // all-ones B fragment for the l row-sum MFMA
  bf16x8 ones;
#pragma unroll
  for (int u = 0; u < 8; ++u) ones[u] = (short)0x3F80;
  const f32x4 fz = {0.f, 0.f, 0.f, 0.f};

  bf16x8 qf[2][2];
  f32x4 oacc[2][4];                             // [is][dt]
  f32x4 lacc[2];

  // prologue: stage unit 0 (tile T0, jt 0) into buf 0
  fa_stage(k, vt, cumn, smem, bn, T0 * 64, 0, 0, tid);

  int ti = T0, jt = 0, i0 = T0 * 64;

  for (int g = 0; g < 33; ++g) {
    const int bsel = g & 1;
    const char* kb = smem + bsel * 16384;
    const char* vb = kb + 8192;
    const float* cumB = (const float*)(smem + 41984) + bsel * 544;
    const int j0 = jt * 64;
    const bool diag = (jt == ti);               // last unit of this tile

    __syncthreads();   // staged data for g visible; buf^1 prior reads done

    // prefetch unit g+1 into the other buffer (flies during this compute)
    if (g + 1 < 33) {
      int gn = g + 1, tin, jtn;
      if (gn < nu0) { tin = T0; jtn = gn; }
      else          { tin = T1; jtn = gn - nu0; }
      fa_stage(k, vt, cumn, smem, bn, tin * 64, jtn * 64, bsel ^ 1, tid);
    }

    if (jt == 0) {
      // new tile: load Q fragments (B-operand for S^T = K*Q^T), reset acc
      const bf16* qbase = q + ((size_t)bn * S_ + i0 + rg * 32) * DH;
#pragma unroll
      for (int is = 0; is < 2; ++is) {
#pragma unroll
        for (int kt = 0; kt < 2; ++kt)
          qf[is][kt] = *(const bf16x8*)(qbase + (is * 16 + lr) * DH + kt * 32 + lq * 8);
        lacc[is] = fz;
#pragma unroll
        for (int dt = 0; dt < 4; ++dt) oacc[is][dt] = fz;
      }
    }

    // S^T = K * Q^T over this wave's 32-col j-chunk; kf shared across is.
    // sa[is][nt][r] = S[i=i0+rg*32+is*16+lr][j=j0+jh*32+nt*16+lq*4+r]
    f32x4 sa[2][2] = {};
#pragma unroll
    for (int kt = 0; kt < 2; ++kt)
#pragma unroll
      for (int nt = 0; nt < 2; ++nt) {
        int krow = jh * 32 + nt * 16 + lr;
        bf16x8 kf = *(const bf16x8*)(kb + krow * 128 +
                        (((kt * 4 + lq) ^ (krow & 7)) << 4));
        sa[0][nt] = MFMA16(kf, qf[0][kt], sa[0][nt]);
        sa[1][nt] = MFMA16(kf, qf[1][kt], sa[1][nt]);
      }

    // p = exp2(s*SCALE2 + cum[i-j]) (no max subtraction), pack, write P.
    // One b128 bias read per reg-quad: Xm3 = 60+ilocI-jl in [0,123],
    // cv[m] = win[Xm3+m], bias(r) = cv[3-r].
    const int doff = i0 - j0;                   // 0 on diag, else >= 64
#pragma unroll
    for (int is = 0; is < 2; ++is) {
      const int ilocI = rg * 32 + is * 16 + lr; // 0..63
      if (!diag) {
#pragma unroll
        for (int nt = 0; nt < 2; ++nt) {
          int jl = jh * 32 + nt * 16 + lq * 4;
          int Xm3 = 60 + ilocI - jl;
          int ph = Xm3 & 3, b0 = Xm3 & ~3;
          f32x4 cv = *(const f32x4*)(cumB + ph * 136 + b0);
          bf16 pk[4];
#pragma unroll
          for (int r = 0; r < 4; ++r)
            pk[r] = __float2bfloat16(exp2f(sa[is][nt][r] * SCALE2 + cv[3 - r]));
          *(uint64_t*)(Ps + ilocI * 72 + jl) = *(const uint64_t*)pk;
        }
      } else {
#pragma unroll
        for (int nt = 0; nt < 2; ++nt) {
          int jl = jh * 32 + nt * 16 + lq * 4;
          int Xm3 = 60 + ilocI - jl;
          int ph = Xm3 & 3, b0 = Xm3 & ~3;
          f32x4 cv = *(const f32x4*)(cumB + ph * 136 + b0);
          bf16 pk[4];
#pragma unroll
          for (int r = 0; r < 4; ++r) {
            float pv = (doff + ilocI - jl - r >= 0)
                           ? exp2f(sa[is][nt][r] * SCALE2 + cv[3 - r])
                           : 0.f;
            pk[r] = __float2bfloat16(pv);
          }
          *(uint64_t*)(Ps + ilocI * 72 + jl) = *(const uint64_t*)pk;
        }
      }
    }

    // O += P V; l += P 1 over the wave's 32-j chunk (one k=32 MFMA step).
    // P rows/cols are wave-private: in-wave DS ordering suffices.
    {
      bf16x8 pf0 = *(const bf16x8*)(Ps + (rg * 32 + lr) * 72 + jh * 32 + lq * 8);
      bf16x8 pf1 = *(const bf16x8*)(Ps + (rg * 32 + 16 + lr) * 72 + jh * 32 + lq * 8);
      lacc[0] = MFMA16(pf0, ones, lacc[0]);
      lacc[1] = MFMA16(pf1, ones, lacc[1]);
#pragma unroll
      for (int dt = 0; dt < 4; ++dt) {
        int vrow = dt * 16 + lr;
        bf16x8 vf = *(const bf16x8*)(vb + vrow * 128 +
                        (((jh * 4 + lq) ^ (vrow & 7)) << 4));
        oacc[0][dt] = MFMA16(pf0, vf, oacc[0][dt]);
        oacc[1][dt] = MFMA16(pf1, vf, oacc[1][dt]);
      }
    }

    if (diag) {
      // tile end: combine j-halves. jh=1 waves export partials into the
      // just-consumed K/V buffer (16KB, free after this barrier).
      __syncthreads();   // all reads of buf bsel complete
      float* scr = (float*)(smem + bsel * 16384) + rg * 2048;  // [32][64]
      if (jh == 1) {
#pragma unroll
        for (int is = 0; is < 2; ++is) {
#pragma unroll
          for (int dt = 0; dt < 4; ++dt)
#pragma unroll
            for (int r = 0; r < 4; ++r) {
              int row = is * 16 + lq * 4 + r;
              int col = ((dt ^ lq) << 4) + lr;   // 2-way-max bank pattern
              scr[row * 64 + col] = oacc[is][dt][r];
            }
          if (lr == 0)
#pragma unroll
            for (int r = 0; r < 4; ++r)
              combL[rg * 32 + is * 16 + lq * 4 + r] = lacc[is][r];
        }
      }
      __syncthreads();   // partials visible
      if (jh == 0) {
#pragma unroll
        for (int is = 0; is < 2; ++is) {
#pragma unroll
          for (int r = 0; r < 4; ++r)
            lacc[is][r] += combL[rg * 32 + is * 16 + lq * 4 + r];
#pragma unroll
          for (int dt = 0; dt < 4; ++dt)
#pragma unroll
            for (int r = 0; r < 4; ++r) {
              int row = is * 16 + lq * 4 + r;
              int col = ((dt ^ lq) << 4) + lr;
              oacc[is][dt][r] += scr[row * 64 + col];
            }
        }
        // store mix[b][s][n][d] for this tile's rows (rg covers 32 rows)
#pragma unroll
        for (int is = 0; is < 2; ++is)
#pragma unroll
          for (int dt = 0; dt < 4; ++dt)
#pragma unroll
            for (int r = 0; r < 4; ++r) {
              int i = i0 + rg * 32 + is * 16 + lq * 4 + r;
              int d = dt * 16 + lr;
              mix[((size_t)(b * S_ + i) * NH + n) * DH + d] =
                  __float2bfloat16(oacc[is][dt][r] / lacc[is][r]);
            }
      }
      ti = T1; jt = 0; i0 = T1 * 64;            // switch to light tile
    } else {
      ++jt;
    }
  }
}

// ---------------------------------------------------------------------------
extern "C" void kernel_launch(void* const* d_in, const int* in_sizes, int n_in,
                              void* d_out, int out_size, void* d_ws, size_t ws_size,
                              hipStream_t stream) {
  const float* x     = (const float*)d_in[0];   // [B,S,H] f32
  const float* qkv   = (const float*)d_in[1];   // [H,3,N,D] f32 == [1024][3072]
  const float* out_w = (const float*)d_in[2];   // [N,D,H] f32   == [1024][1024]
  const float* rpe   = (const float*)d_in[3];   // [N,S] f32
  float* out = (float*)d_out;                   // [B,S,H] f32

  char* ws = (char*)d_ws;
  bf16* qkvT  = (bf16*)(ws + 0);          // [3072][1024] bf16   6291456 B
  bf16* outwT = (bf16*)(ws + 6291456);    // [1024][1024] bf16   2097152 B
  bf16* xb    = (bf16*)(ws + 8388608);    // [4096][1024] bf16   8388608 B
  bf16* qb    = (bf16*)(ws + 16777216);   // [bn][S][D]          8388608 B
  bf16* kb    = (bf16*)(ws + 25165824);   // [bn][S][D]          8388608 B
  bf16* vtb   = (bf16*)(ws + 33554432);   // [bn][D][S]          8388608 B
  bf16* mixb  = (bf16*)(ws + 41943040);   // [b][s][n][d]        8388608 B
  float* cum  = (float*)(ws + 50331648);  // [N][S] f32 (xLOG2E)  131072 B

  // 1. fused prep: convert x, transpose+convert weights, rpe cumsum
  prep<<<8208, 256, 0, stream>>>(x, xb, qkv, qkvT, out_w, outwT, rpe, cum);
  // 2. QKV projection (V written pre-transposed; 768 blocks = 3/CU, no tail)
  gemm_bt<0><<<dim3(3072 / 128, 4096 / 128), 256, 0, stream>>>(xb, qkvT, qb, kb, vtb, nullptr);
  // 3. attention: 512 blocks, each exactly 33 64x64-units (pair {31-p, p}),
  //    2 blocks/CU co-resident with equal duration, dbuf + j-split waves
  fa_kernel<<<512, 256, 0, stream>>>(qb, kb, vtb, cum, mixb);
  // 4. output projection (f32 out; 128x64 tiles -> 512 blocks = 2/CU)
  gemm_bt<1><<<dim3(1024 / 64, 4096 / 128), 256, 0, stream>>>(mixb, outwT, nullptr, nullptr, nullptr, out);
}

// Round 6
// 182.359 us; speedup vs baseline: 1.1275x; 1.0135x over previous
//
#include <hip/hip_runtime.h>
#include <hip/hip_bf16.h>
#include <cstdint>
#include <cstddef>

// Problem constants
#define B_   2
#define S_   2048
#define H_   1024
#define NH   16
#define DH   64
#define LOG2E 1.4426950408889634f
#define SCALE2 (0.125f * LOG2E)   // D^-0.5 * log2(e): softmax done in exp2 domain

typedef __hip_bfloat16 bf16;
typedef short bf16x8 __attribute__((ext_vector_type(8)));   // 8 bf16 in 4 VGPRs
typedef float f32x4 __attribute__((ext_vector_type(4)));

#define MFMA16(a, b, c) __builtin_amdgcn_mfma_f32_16x16x32_bf16((a), (b), (c), 0, 0, 0)

__device__ __forceinline__ void async16(const void* g, void* l) {
  __builtin_amdgcn_global_load_lds(
      (const __attribute__((address_space(1))) void*)g,
      (__attribute__((address_space(3))) void*)l,
      16, 0, 0);
}
__device__ __forceinline__ void async4(const void* g, void* l) {
  __builtin_amdgcn_global_load_lds(
      (const __attribute__((address_space(1))) void*)g,
      (__attribute__((address_space(3))) void*)l,
      4, 0, 0);
}

__device__ __forceinline__ short bf16bits(float v) {
  bf16 t = __float2bfloat16(v);
  return *reinterpret_cast<short*>(&t);
}

// ---------------------------------------------------------------------------
// Fused prep kernel (one dispatch, grid 8208) — unchanged.
// ---------------------------------------------------------------------------
__device__ __forceinline__ void tr_body(const float* __restrict__ src,
                                        bf16* __restrict__ dst, int R, int C,
                                        int c0, int r0, bf16 (*tile)[33], int tid) {
  int tx = tid & 31, ty = tid >> 5;   // 32 x 8
  for (int i = 0; i < 32; i += 8)
    tile[ty + i][tx] = __float2bfloat16(src[(size_t)(r0 + ty + i) * C + c0 + tx]);
  __syncthreads();
  for (int i = 0; i < 32; i += 8)
    dst[(size_t)(c0 + ty + i) * R + r0 + tx] = tile[tx][ty + i];
}

__global__ __launch_bounds__(256)
void prep(const float* __restrict__ x, bf16* __restrict__ xb,
          const float* __restrict__ qkv, bf16* __restrict__ qkvT,
          const float* __restrict__ outw, bf16* __restrict__ outwT,
          const float* __restrict__ rpe, float* __restrict__ cum) {
  __shared__ char pm[2176] __attribute__((aligned(16)));
  const int L = blockIdx.x, tid = threadIdx.x;
  if (L < 4096) {
    int i = (L * 256 + tid) * 4;
    float4 v = *(const float4*)(x + i);
    bf16 o[4] = {__float2bfloat16(v.x), __float2bfloat16(v.y),
                 __float2bfloat16(v.z), __float2bfloat16(v.w)};
    *(uint64_t*)(xb + i) = *(const uint64_t*)o;
  } else if (L < 7168) {
    int t = L - 4096;
    int cx = t % 96, ry = t / 96;
    tr_body(qkv, qkvT, 1024, 3072, cx * 32, ry * 32, (bf16(*)[33])pm, tid);
  } else if (L < 8192) {
    int t = L - 7168;
    int cx = t & 31, ry = t >> 5;
    tr_body(outw, outwT, 1024, 1024, cx * 32, ry * 32, (bf16(*)[33])pm, tid);
  } else {
    // rpe cumsum (scaled by LOG2E)
    float* ssum = (float*)pm;
    int n = L - 8192;
    float loc[8];
    float s = 0.f;
    int base = tid * 8;
#pragma unroll
    for (int u = 0; u < 8; ++u) {
      loc[u] = rpe[n * S_ + base + u];
      s += loc[u];
    }
    ssum[tid] = s;
    __syncthreads();
    float own = s;
    for (int off = 1; off < 256; off <<= 1) {
      float v = (tid >= off) ? ssum[tid - off] : 0.f;
      __syncthreads();
      ssum[tid] += v;
      __syncthreads();
    }
    float run = ssum[tid] - own;   // exclusive prefix of this thread's chunk
#pragma unroll
    for (int u = 0; u < 8; ++u) {
      run += loc[u];
      cum[n * S_ + base + u] = run * LOG2E;
    }
  }
}

// ---------------------------------------------------------------------------
// GEMM — unchanged.
// ---------------------------------------------------------------------------
template <int MODE>
__global__ __launch_bounds__(256, MODE == 0 ? 3 : 2)
void gemm_bt(const bf16* __restrict__ A, const bf16* __restrict__ Bt,
             bf16* __restrict__ C0, bf16* __restrict__ C1, bf16* __restrict__ C2,
             float* __restrict__ F0) {
  constexpr int NT = (MODE == 0) ? 4 : 2;     // n-subtiles per wave
  constexpr int NB = NT * 32;                 // block n-extent: 128 or 64
  __shared__ char smem[MODE == 0 ? 36864 : 12288] __attribute__((aligned(16)));
  bf16* As = (bf16*)smem;              // [128*32]
  bf16* Bs = (bf16*)(smem + 8192);     // [NB*32]
  const int tid = threadIdx.x, lane = tid & 63, w = tid >> 6;
  const int lr = lane & 15, lq = lane >> 4;
  const int m0 = blockIdx.y * 128, n0 = blockIdx.x * NB;
  const int wm = (w & 1) * 64, wn = (w >> 1) * (NT * 16);

  f32x4 acc[4][NT] = {};

  for (int k0 = 0; k0 < 1024; k0 += 32) {
    __syncthreads();
#pragma unroll
    for (int t = 0; t < 2; ++t) {
      int c = (t * 4 + w) * 64 + lane;          // 16B-chunk id 0..511
      int row = c >> 2, ch = c & 3;
      int k8 = (ch ^ ((row >> 1) & 3)) * 8;     // swizzled source chunk
      async16(A + (size_t)(m0 + row) * 1024 + k0 + k8,
              (char*)As + (size_t)(t * 4 + w) * 1024 + lane * 16);
    }
#pragma unroll
    for (int t = 0; t < NB / 64; ++t) {
      int c = (t * 4 + w) * 64 + lane;          // chunk id, NB*4 total
      int row = c >> 2, ch = c & 3;
      int k8 = (ch ^ ((row >> 1) & 3)) * 8;
      async16(Bt + (size_t)(n0 + row) * 1024 + k0 + k8,
              (char*)Bs + (size_t)(t * 4 + w) * 1024 + lane * 16);
    }
    __syncthreads();
    bf16x8 af[4], bfr[NT];
#pragma unroll
    for (int mt = 0; mt < 4; ++mt) {
      int row = wm + mt * 16 + lr;
      af[mt] = *(const bf16x8*)(As + row * 32 + ((lq ^ ((row >> 1) & 3)) << 3));
    }
#pragma unroll
    for (int nt = 0; nt < NT; ++nt) {
      int row = wn + nt * 16 + lr;
      bfr[nt] = *(const bf16x8*)(Bs + row * 32 + ((lq ^ ((row >> 1) & 3)) << 3));
    }
#pragma unroll
    for (int mt = 0; mt < 4; ++mt)
#pragma unroll
      for (int nt = 0; nt < NT; ++nt)
        acc[mt][nt] = MFMA16(af[mt], bfr[nt], acc[mt][nt]);
  }

  if (MODE == 0) {
    __syncthreads();   // all As/Bs reads done; reuse LDS for epilogue tiles
    bf16* E = (bf16*)smem + w * (64 * 72);   // wave-private [64][72]
    const int cbase = n0 + wn;               // 64-aligned
    const int mm = cbase >> 10, nn = (cbase >> 6) & 15;
    const int bb = (m0 + wm) >> 11;
    const int sbase = (m0 + wm) & 2047;
    if (mm < 2) {
      // write acc as [s][d] into E
#pragma unroll
      for (int mt = 0; mt < 4; ++mt)
#pragma unroll
        for (int nt = 0; nt < 4; ++nt)
#pragma unroll
          for (int r = 0; r < 4; ++r)
            E[(mt * 16 + lq * 4 + r) * 72 + nt * 16 + lr] =
                __float2bfloat16(acc[mt][nt][r]);
      // wave-private readback (in-wave lgkm ordering), b128 stores
      bf16* dst = (mm == 0 ? C0 : C1) +
                  ((size_t)(bb * NH + nn) * S_ + sbase) * DH;
#pragma unroll
      for (int it = 0; it < 8; ++it) {
        int c = it * 64 + lane;
        int rw = c >> 3, c8 = c & 7;
        *(uint4*)(dst + (size_t)rw * DH + c8 * 8) =
            *(const uint4*)(E + rw * 72 + c8 * 8);
      }
    } else {
      // V: write acc as [d][s] into E
#pragma unroll
      for (int mt = 0; mt < 4; ++mt)
#pragma unroll
        for (int nt = 0; nt < 4; ++nt)
#pragma unroll
          for (int r = 0; r < 4; ++r)
            E[(nt * 16 + lr) * 72 + mt * 16 + lq * 4 + r] =
                __float2bfloat16(acc[mt][nt][r]);
      bf16* dst = C2 + (size_t)(bb * NH + nn) * DH * S_;
#pragma unroll
      for (int it = 0; it < 8; ++it) {
        int c = it * 64 + lane;
        int dr = c >> 3, c8 = c & 7;
        *(uint4*)(dst + (size_t)dr * S_ + sbase + c8 * 8) =
            *(const uint4*)(E + dr * 72 + c8 * 8);
      }
    }
  } else {
#pragma unroll
    for (int mt = 0; mt < 4; ++mt)
#pragma unroll
      for (int nt = 0; nt < NT; ++nt)
#pragma unroll
        for (int r = 0; r < 4; ++r) {
          int rM = m0 + wm + mt * 16 + lq * 4 + r;
          int cN = n0 + wn + nt * 16 + lr;
          F0[(size_t)rM * 1024 + cN] = acc[mt][nt][r];
        }
  }
}

// ---------------------------------------------------------------------------
// Flash attention, R6: R5 + IN-REGISTER P via permuted-K rows (no P LDS).
// R5 post-mortem: per-unit cost identical to R1 despite fewer DS instr ->
// the limiter is the serial chain, dominated by the P LDS round-trip
// (pack -> ds_write -> lgkm -> ds_read). Fix: in S^T = K*Q^T the C-row p
// pulls from A-row p, and we choose which K row each A-row loads. Loading
// jrow(p) = (p>>2)*8 + nt*4 + (p&3) makes lane (lr,lq)'s softmax output
// P[i=ibase+lr][j=jc0+lq*8+(nt*4+r)] — exactly the PV A-fragment layout
// (row=lane&15, k=lq*8+u). pf is built in registers; P never touches LDS.
// Row-sum MFMA (P*ones) is permutation-invariant; bias read carries over
// with jl = jh*32+lq*8+nt*4; diag mask is per-element.
// K swizzle key change: permuted rows {0-3,8-11,16-19,24-27}+nt*4 make
// the old ch^(row&7) key collapse to 4 values (2x read conflict); use
// kk(row) = (row&3)|((row>>1)&4) (row bit3 -> key bit2): 8 values, full
// bank spread on both stage and read. V swizzle unchanged (row&7).
// Equal-duration pairing {31-p, p} = 33 units, 512 blocks, dbuf prefetch,
// single barrier/unit, j-split waves + additive tile-end combine: all kept.
// LDS: K/V dbuf [0,32768); cum [2][4][136] f32 [32768,37120);
//      combL [2][32] f32 [37120,37376).
// ---------------------------------------------------------------------------
__device__ __forceinline__ void fa_stage(const bf16* __restrict__ k,
                                         const bf16* __restrict__ vt,
                                         const float* __restrict__ cumn,
                                         char* smem, int bn, int i0, int j0,
                                         int buf, int tid) {
  char* dst = smem + buf * 16384;
  // K tile: rows j0..j0+63 (128B each, 8 chunks); slot (row,ch) holds
  // global chunk ch^kk(row), kk = (row&3)|((row>>1)&4). 512 chunks.
  const char* ksrc = (const char*)(k + ((size_t)bn * S_ + j0) * DH);
#pragma unroll
  for (int t = 0; t < 2; ++t) {
    int c = t * 256 + tid;                    // 0..511
    int row = c >> 3, ch = c & 7;
    int cs = ch ^ ((row & 3) | ((row >> 1) & 4));
    async16(ksrc + row * 128 + cs * 16, dst + c * 16);
  }
  // Vt tile: d rows 0..63, cols j0..j0+63 (128B each); slot (d,ch) holds
  // global chunk ch^(d&7).
  const char* vsrc = (const char*)(vt + (size_t)bn * DH * S_);
#pragma unroll
  for (int t = 0; t < 2; ++t) {
    int c = t * 256 + tid;
    int row = c >> 3, ch = c & 7;             // row = d index
    int cs = ch ^ (row & 7);
    async16(vsrc + (size_t)row * (S_ * 2) + j0 * 2 + cs * 16,
            dst + 8192 + c * 16);
  }
  // cum windows: cumS[buf][p][t] = cumn[clamp(i0-j0-63 + t + p)], t=tid<136.
  // Stride 136 words == 8 mod 32 banks.
  if (tid < 136) {
    float* cdst = (float*)(smem + 32768) + buf * 544;  // 4*136
    int base = i0 - j0 - 63 + tid;
#pragma unroll
    for (int p = 0; p < 4; ++p) {
      int src = base + p;
      src = src < 0 ? 0 : (src > S_ - 1 ? S_ - 1 : src);
      async4(cumn + src, cdst + p * 136 + tid);
    }
  }
}

__global__ __launch_bounds__(256, 2)
void fa_kernel(const bf16* __restrict__ q, const bf16* __restrict__ k,
               const bf16* __restrict__ vt, const float* __restrict__ cum,
               bf16* __restrict__ mix) {
  __shared__ char smem[37376] __attribute__((aligned(16)));
  float* combL = (float*)(smem + 37120);        // [2][32]

  const int tid = threadIdx.x, lane = tid & 63, w = tid >> 6;  // w: 0..3
  const int lr = lane & 15, lq = lane >> 4;
  const int rg = w & 1, jh = w >> 1;            // row-group, j-half

  const int L = blockIdx.x;                     // 0..511
  const int xcd = L & 7, slot = L >> 3;         // slot 0..63
  const int bn = xcd + 8 * (slot & 3);          // 4 heads per XCD
  const int pp = slot >> 2;                     // pair index 0..15
  const int n = bn & (NH - 1);
  const int b = bn >> 4;
  const float* cumn = cum + n * S_;

  const int T0 = 31 - pp;                       // heavy tile (32-pp units)
  const int T1 = pp;                            // light tile (pp+1 units)
  const int nu0 = T0 + 1;                       // units in tile 0

  // all-ones B fragment for the l row-sum MFMA
  bf16x8 ones;
#pragma unroll
  for (int u = 0; u < 8; ++u) ones[u] = (short)0x3F80;
  const f32x4 fz = {0.f, 0.f, 0.f, 0.f};

  // permuted-K swizzle key: kk = (lr&3) | (((lr>>2)&1)<<2), row-bit3 based
  const int kkey = (lr & 3) | (((lr >> 2) & 1) << 2);

  bf16x8 qf[2][2];
  f32x4 oacc[2][4];                             // [is][dt]
  f32x4 lacc[2];

  // prologue: stage unit 0 (tile T0, jt 0) into buf 0
  fa_stage(k, vt, cumn, smem, bn, T0 * 64, 0, 0, tid);

  int ti = T0, jt = 0, i0 = T0 * 64;

  for (int g = 0; g < 33; ++g) {
    const int bsel = g & 1;
    const char* kb = smem + bsel * 16384;
    const char* vb = kb + 8192;
    const float* cumB = (const float*)(smem + 32768) + bsel * 544;
    const int j0 = jt * 64;
    const bool diag = (jt == ti);               // last unit of this tile

    __syncthreads();   // staged data for g visible; buf^1 prior reads done

    // prefetch unit g+1 into the other buffer (flies during this compute)
    if (g + 1 < 33) {
      int gn = g + 1, tin, jtn;
      if (gn < nu0) { tin = T0; jtn = gn; }
      else          { tin = T1; jtn = gn - nu0; }
      fa_stage(k, vt, cumn, smem, bn, tin * 64, jtn * 64, bsel ^ 1, tid);
    }

    if (jt == 0) {
      // new tile: load Q fragments (B-operand for S^T = K*Q^T), reset acc
      const bf16* qbase = q + ((size_t)bn * S_ + i0 + rg * 32) * DH;
#pragma unroll
      for (int is = 0; is < 2; ++is) {
#pragma unroll
        for (int kt = 0; kt < 2; ++kt)
          qf[is][kt] = *(const bf16x8*)(qbase + (is * 16 + lr) * DH + kt * 32 + lq * 8);
        lacc[is] = fz;
#pragma unroll
        for (int dt = 0; dt < 4; ++dt) oacc[is][dt] = fz;
      }
    }

    // S^T = K * Q^T with PERMUTED K rows: A-row lr of MFMA nt loads
    // krow = jh*32 + (lr>>2)*8 + nt*4 + (lr&3), so C position (lq*4+r)
    // holds j = jh*32 + lq*8 + nt*4 + r — the PV A-fragment layout.
    f32x4 sa[2][2] = {};
#pragma unroll
    for (int kt = 0; kt < 2; ++kt)
#pragma unroll
      for (int nt = 0; nt < 2; ++nt) {
        int krow = jh * 32 + ((lr >> 2) << 3) + nt * 4 + (lr & 3);
        bf16x8 kf = *(const bf16x8*)(kb + krow * 128 +
                        (((kt * 4 + lq) ^ kkey) << 4));
        sa[0][nt] = MFMA16(kf, qf[0][kt], sa[0][nt]);
        sa[1][nt] = MFMA16(kf, qf[1][kt], sa[1][nt]);
      }

    // p = exp2(s*SCALE2 + cum[i-j]) (no max subtraction), straight into
    // the PV A-fragment registers. One b128 bias read per reg-quad:
    // Xm3 = 60 + ilocI - jl, cv[m] = win[Xm3+m], bias(r) = cv[3-r].
    const int doff = i0 - j0;                   // 0 on diag, else >= 64
    bf16x8 pf[2];
#pragma unroll
    for (int is = 0; is < 2; ++is) {
      const int ilocI = rg * 32 + is * 16 + lr; // 0..63
#pragma unroll
      for (int nt = 0; nt < 2; ++nt) {
        int jl = jh * 32 + lq * 8 + nt * 4;
        int Xm3 = 60 + ilocI - jl;
        int ph = Xm3 & 3, b0 = Xm3 & ~3;
        f32x4 cv = *(const f32x4*)(cumB + ph * 136 + b0);
        if (!diag) {
#pragma unroll
          for (int r = 0; r < 4; ++r)
            pf[is][nt * 4 + r] =
                bf16bits(exp2f(sa[is][nt][r] * SCALE2 + cv[3 - r]));
        } else {
#pragma unroll
          for (int r = 0; r < 4; ++r) {
            float pv = (doff + ilocI - jl - r >= 0)
                           ? exp2f(sa[is][nt][r] * SCALE2 + cv[3 - r])
                           : 0.f;
            pf[is][nt * 4 + r] = bf16bits(pv);
          }
        }
      }
    }

    // O += P V; l += P 1 — pf straight from registers, no LDS.
    lacc[0] = MFMA16(pf[0], ones, lacc[0]);
    lacc[1] = MFMA16(pf[1], ones, lacc[1]);
#pragma unroll
    for (int dt = 0; dt < 4; ++dt) {
      int vrow = dt * 16 + lr;
      bf16x8 vf = *(const bf16x8*)(vb + vrow * 128 +
                      (((jh * 4 + lq) ^ (vrow & 7)) << 4));
      oacc[0][dt] = MFMA16(pf[0], vf, oacc[0][dt]);
      oacc[1][dt] = MFMA16(pf[1], vf, oacc[1][dt]);
    }

    if (diag) {
      // tile end: combine j-halves. jh=1 waves export partials into the
      // just-consumed K/V buffer (16KB, free after this barrier).
      __syncthreads();   // all reads of buf bsel complete
      float* scr = (float*)(smem + bsel * 16384) + rg * 2048;  // [32][64]
      if (jh == 1) {
#pragma unroll
        for (int is = 0; is < 2; ++is) {
#pragma unroll
          for (int dt = 0; dt < 4; ++dt)
#pragma unroll
            for (int r = 0; r < 4; ++r) {
              int row = is * 16 + lq * 4 + r;
              int col = ((dt ^ lq) << 4) + lr;   // 2-way-max bank pattern
              scr[row * 64 + col] = oacc[is][dt][r];
            }
          if (lr == 0)
#pragma unroll
            for (int r = 0; r < 4; ++r)
              combL[rg * 32 + is * 16 + lq * 4 + r] = lacc[is][r];
        }
      }
      __syncthreads();   // partials visible
      if (jh == 0) {
#pragma unroll
        for (int is = 0; is < 2; ++is) {
#pragma unroll
          for (int r = 0; r < 4; ++r)
            lacc[is][r] += combL[rg * 32 + is * 16 + lq * 4 + r];
#pragma unroll
          for (int dt = 0; dt < 4; ++dt)
#pragma unroll
            for (int r = 0; r < 4; ++r) {
              int row = is * 16 + lq * 4 + r;
              int col = ((dt ^ lq) << 4) + lr;
              oacc[is][dt][r] += scr[row * 64 + col];
            }
        }
        // store mix[b][s][n][d] for this tile's rows (rg covers 32 rows)
#pragma unroll
        for (int is = 0; is < 2; ++is)
#pragma unroll
          for (int dt = 0; dt < 4; ++dt)
#pragma unroll
            for (int r = 0; r < 4; ++r) {
              int i = i0 + rg * 32 + is * 16 + lq * 4 + r;
              int d = dt * 16 + lr;
              mix[((size_t)(b * S_ + i) * NH + n) * DH + d] =
                  __float2bfloat16(oacc[is][dt][r] / lacc[is][r]);
            }
      }
      ti = T1; jt = 0; i0 = T1 * 64;            // switch to light tile
    } else {
      ++jt;
    }
  }
}

// ---------------------------------------------------------------------------
extern "C" void kernel_launch(void* const* d_in, const int* in_sizes, int n_in,
                              void* d_out, int out_size, void* d_ws, size_t ws_size,
                              hipStream_t stream) {
  const float* x     = (const float*)d_in[0];   // [B,S,H] f32
  const float* qkv   = (const float*)d_in[1];   // [H,3,N,D] f32 == [1024][3072]
  const float* out_w = (const float*)d_in[2];   // [N,D,H] f32   == [1024][1024]
  const float* rpe   = (const float*)d_in[3];   // [N,S] f32
  float* out = (float*)d_out;                   // [B,S,H] f32

  char* ws = (char*)d_ws;
  bf16* qkvT  = (bf16*)(ws + 0);          // [3072][1024] bf16   6291456 B
  bf16* outwT = (bf16*)(ws + 6291456);    // [1024][1024] bf16   2097152 B
  bf16* xb    = (bf16*)(ws + 8388608);    // [4096][1024] bf16   8388608 B
  bf16* qb    = (bf16*)(ws + 16777216);   // [bn][S][D]          8388608 B
  bf16* kb    = (bf16*)(ws + 25165824);   // [bn][S][D]          8388608 B
  bf16* vtb   = (bf16*)(ws + 33554432);   // [bn][D][S]          8388608 B
  bf16* mixb  = (bf16*)(ws + 41943040);   // [b][s][n][d]        8388608 B
  float* cum  = (float*)(ws + 50331648);  // [N][S] f32 (xLOG2E)  131072 B

  // 1. fused prep: convert x, transpose+convert weights, rpe cumsum
  prep<<<8208, 256, 0, stream>>>(x, xb, qkv, qkvT, out_w, outwT, rpe, cum);
  // 2. QKV projection (V written pre-transposed; 768 blocks = 3/CU, no tail)
  gemm_bt<0><<<dim3(3072 / 128, 4096 / 128), 256, 0, stream>>>(xb, qkvT, qb, kb, vtb, nullptr);
  // 3. attention: 512 blocks, each exactly 33 64x64-units (pair {31-p, p}),
  //    2 blocks/CU equal-duration, dbuf, in-register P via permuted K rows
  fa_kernel<<<512, 256, 0, stream>>>(qb, kb, vtb, cum, mixb);
  // 4. output projection (f32 out; 128x64 tiles -> 512 blocks = 2/CU)
  gemm_bt<1><<<dim3(1024 / 64, 4096 / 128), 256, 0, stream>>>(mixb, outwT, nullptr, nullptr, nullptr, out);
}

// Round 7
// 178.536 us; speedup vs baseline: 1.1517x; 1.0214x over previous
//
#include <hip/hip_runtime.h>
#include <hip/hip_bf16.h>
#include <cstdint>
#include <cstddef>

// Problem constants
#define B_   2
#define S_   2048
#define H_   1024
#define NH   16
#define DH   64
#define LOG2E 1.4426950408889634f
#define SCALE2 (0.125f * LOG2E)   // D^-0.5 * log2(e): softmax done in exp2 domain

typedef __hip_bfloat16 bf16;
typedef short bf16x8 __attribute__((ext_vector_type(8)));   // 8 bf16 in 4 VGPRs
typedef float f32x4 __attribute__((ext_vector_type(4)));

#define MFMA16(a, b, c) __builtin_amdgcn_mfma_f32_16x16x32_bf16((a), (b), (c), 0, 0, 0)

__device__ __forceinline__ void async16(const void* g, void* l) {
  __builtin_amdgcn_global_load_lds(
      (const __attribute__((address_space(1))) void*)g,
      (__attribute__((address_space(3))) void*)l,
      16, 0, 0);
}
__device__ __forceinline__ void async4(const void* g, void* l) {
  __builtin_amdgcn_global_load_lds(
      (const __attribute__((address_space(1))) void*)g,
      (__attribute__((address_space(3))) void*)l,
      4, 0, 0);
}

__device__ __forceinline__ short bf16bits(float v) {
  bf16 t = __float2bfloat16(v);
  return *reinterpret_cast<short*>(&t);
}

// ---------------------------------------------------------------------------
// Fused prep kernel (one dispatch, grid 8208) — unchanged.
// ---------------------------------------------------------------------------
__device__ __forceinline__ void tr_body(const float* __restrict__ src,
                                        bf16* __restrict__ dst, int R, int C,
                                        int c0, int r0, bf16 (*tile)[33], int tid) {
  int tx = tid & 31, ty = tid >> 5;   // 32 x 8
  for (int i = 0; i < 32; i += 8)
    tile[ty + i][tx] = __float2bfloat16(src[(size_t)(r0 + ty + i) * C + c0 + tx]);
  __syncthreads();
  for (int i = 0; i < 32; i += 8)
    dst[(size_t)(c0 + ty + i) * R + r0 + tx] = tile[tx][ty + i];
}

__global__ __launch_bounds__(256)
void prep(const float* __restrict__ x, bf16* __restrict__ xb,
          const float* __restrict__ qkv, bf16* __restrict__ qkvT,
          const float* __restrict__ outw, bf16* __restrict__ outwT,
          const float* __restrict__ rpe, float* __restrict__ cum) {
  __shared__ char pm[2176] __attribute__((aligned(16)));
  const int L = blockIdx.x, tid = threadIdx.x;
  if (L < 4096) {
    int i = (L * 256 + tid) * 4;
    float4 v = *(const float4*)(x + i);
    bf16 o[4] = {__float2bfloat16(v.x), __float2bfloat16(v.y),
                 __float2bfloat16(v.z), __float2bfloat16(v.w)};
    *(uint64_t*)(xb + i) = *(const uint64_t*)o;
  } else if (L < 7168) {
    int t = L - 4096;
    int cx = t % 96, ry = t / 96;
    tr_body(qkv, qkvT, 1024, 3072, cx * 32, ry * 32, (bf16(*)[33])pm, tid);
  } else if (L < 8192) {
    int t = L - 7168;
    int cx = t & 31, ry = t >> 5;
    tr_body(outw, outwT, 1024, 1024, cx * 32, ry * 32, (bf16(*)[33])pm, tid);
  } else {
    // rpe cumsum (scaled by LOG2E)
    float* ssum = (float*)pm;
    int n = L - 8192;
    float loc[8];
    float s = 0.f;
    int base = tid * 8;
#pragma unroll
    for (int u = 0; u < 8; ++u) {
      loc[u] = rpe[n * S_ + base + u];
      s += loc[u];
    }
    ssum[tid] = s;
    __syncthreads();
    float own = s;
    for (int off = 1; off < 256; off <<= 1) {
      float v = (tid >= off) ? ssum[tid - off] : 0.f;
      __syncthreads();
      ssum[tid] += v;
      __syncthreads();
    }
    float run = ssum[tid] - own;   // exclusive prefix of this thread's chunk
#pragma unroll
    for (int u = 0; u < 8; ++u) {
      run += loc[u];
      cum[n * S_ + base + u] = run * LOG2E;
    }
  }
}

// ---------------------------------------------------------------------------
// GEMM: C[M x Nc] = A[M x 1024] * Bt[Nc x 1024]^T, bf16 in, f32 acc.
// R7: BK=64 (was 32) — 2x MFMA per barrier (32/wave MODE0), K-steps 16.
// 128B LDS rows, 8 chunks; stage slot(row,ch) holds chunk ch^(row&7);
// read chunk (kt*4+lq)^(row&7): 2-way max (free). MODE0 main LDS 32KB
// (epilogue's 36.9KB still dominates) -> 3 blocks/CU kept; MODE1 24.6KB.
// ---------------------------------------------------------------------------
template <int MODE>
__global__ __launch_bounds__(256, MODE == 0 ? 3 : 2)
void gemm_bt(const bf16* __restrict__ A, const bf16* __restrict__ Bt,
             bf16* __restrict__ C0, bf16* __restrict__ C1, bf16* __restrict__ C2,
             float* __restrict__ F0) {
  constexpr int NT = (MODE == 0) ? 4 : 2;     // n-subtiles per wave
  constexpr int NB = NT * 32;                 // block n-extent: 128 or 64
  __shared__ char smem[MODE == 0 ? 36864 : 24576] __attribute__((aligned(16)));
  bf16* As = (bf16*)smem;              // [128][64]
  bf16* Bs = (bf16*)(smem + 16384);    // [NB][64]
  const int tid = threadIdx.x, lane = tid & 63, w = tid >> 6;
  const int lr = lane & 15, lq = lane >> 4;
  const int m0 = blockIdx.y * 128, n0 = blockIdx.x * NB;
  const int wm = (w & 1) * 64, wn = (w >> 1) * (NT * 16);

  f32x4 acc[4][NT] = {};

  for (int k0 = 0; k0 < 1024; k0 += 64) {
    __syncthreads();
    // A tile: 128 rows x 64 bf16 (8 chunks/row) = 1024 chunks
#pragma unroll
    for (int t = 0; t < 4; ++t) {
      int c = t * 256 + tid;
      int row = c >> 3, ch = c & 7;
      int cs = ch ^ (row & 7);
      async16(A + (size_t)(m0 + row) * 1024 + k0 + cs * 8,
              (char*)As + c * 16);
    }
    // B tile: NB rows x 64 bf16
#pragma unroll
    for (int t = 0; t < NB / 32; ++t) {
      int c = t * 256 + tid;
      int row = c >> 3, ch = c & 7;
      int cs = ch ^ (row & 7);
      async16(Bt + (size_t)(n0 + row) * 1024 + k0 + cs * 8,
              (char*)Bs + c * 16);
    }
    __syncthreads();
    bf16x8 af[4][2], bfr[NT][2];
#pragma unroll
    for (int mt = 0; mt < 4; ++mt) {
      int row = wm + mt * 16 + lr;
#pragma unroll
      for (int kt = 0; kt < 2; ++kt)
        af[mt][kt] = *(const bf16x8*)(As + row * 64 +
                         (((kt * 4 + lq) ^ (row & 7)) << 3));
    }
#pragma unroll
    for (int nt = 0; nt < NT; ++nt) {
      int row = wn + nt * 16 + lr;
#pragma unroll
      for (int kt = 0; kt < 2; ++kt)
        bfr[nt][kt] = *(const bf16x8*)(Bs + row * 64 +
                          (((kt * 4 + lq) ^ (row & 7)) << 3));
    }
#pragma unroll
    for (int mt = 0; mt < 4; ++mt)
#pragma unroll
      for (int nt = 0; nt < NT; ++nt)
#pragma unroll
        for (int kt = 0; kt < 2; ++kt)
          acc[mt][nt] = MFMA16(af[mt][kt], bfr[nt][kt], acc[mt][nt]);
  }

  if (MODE == 0) {
    __syncthreads();   // all As/Bs reads done; reuse LDS for epilogue tiles
    bf16* E = (bf16*)smem + w * (64 * 72);   // wave-private [64][72]
    const int cbase = n0 + wn;               // 64-aligned
    const int mm = cbase >> 10, nn = (cbase >> 6) & 15;
    const int bb = (m0 + wm) >> 11;
    const int sbase = (m0 + wm) & 2047;
    if (mm < 2) {
      // write acc as [s][d] into E
#pragma unroll
      for (int mt = 0; mt < 4; ++mt)
#pragma unroll
        for (int nt = 0; nt < 4; ++nt)
#pragma unroll
          for (int r = 0; r < 4; ++r)
            E[(mt * 16 + lq * 4 + r) * 72 + nt * 16 + lr] =
                __float2bfloat16(acc[mt][nt][r]);
      // wave-private readback (in-wave lgkm ordering), b128 stores
      bf16* dst = (mm == 0 ? C0 : C1) +
                  ((size_t)(bb * NH + nn) * S_ + sbase) * DH;
#pragma unroll
      for (int it = 0; it < 8; ++it) {
        int c = it * 64 + lane;
        int rw = c >> 3, c8 = c & 7;
        *(uint4*)(dst + (size_t)rw * DH + c8 * 8) =
            *(const uint4*)(E + rw * 72 + c8 * 8);
      }
    } else {
      // V: write acc as [d][s] into E
#pragma unroll
      for (int mt = 0; mt < 4; ++mt)
#pragma unroll
        for (int nt = 0; nt < 4; ++nt)
#pragma unroll
          for (int r = 0; r < 4; ++r)
            E[(nt * 16 + lr) * 72 + mt * 16 + lq * 4 + r] =
                __float2bfloat16(acc[mt][nt][r]);
      bf16* dst = C2 + (size_t)(bb * NH + nn) * DH * S_;
#pragma unroll
      for (int it = 0; it < 8; ++it) {
        int c = it * 64 + lane;
        int dr = c >> 3, c8 = c & 7;
        *(uint4*)(dst + (size_t)dr * S_ + sbase + c8 * 8) =
            *(const uint4*)(E + dr * 72 + c8 * 8);
      }
    }
  } else {
#pragma unroll
    for (int mt = 0; mt < 4; ++mt)
#pragma unroll
      for (int nt = 0; nt < NT; ++nt)
#pragma unroll
        for (int r = 0; r < 4; ++r) {
          int rM = m0 + wm + mt * 16 + lq * 4 + r;
          int cN = n0 + wn + nt * 16 + lr;
          F0[(size_t)rM * 1024 + cN] = acc[mt][nt][r];
        }
  }
}

// ---------------------------------------------------------------------------
// Flash attention, R7: R6 (in-register P, equal-duration pairing, dbuf
// prefetch) with 128-COL KV UNITS — 2x work per barrier. R6 post-mortem:
// three structures all ~54-56us, no pipe >45% busy -> barrier/drain-bound
// (37 barriers/block, ~2000cyc apart). Fix: barriers/block 37 -> 21.
// units(t) = ceil((t+1)/2); pair {31-p, p} = 17 units for every p.
// Per wave-unit: 16 QK MFMA + 4 lacc + 16 PV = 36 MFMA between barriers.
// In-reg P: krow = jh*64 + kt*32 + (lr>>2)*8 + nt2*4 + (lr&3); swizzle key
// kkey = (lr&3)|(((lr>>2)&1)<<2) independent of kt/nt2 (bit-3 = lr bit2).
// V tile [64 d][256B], key vrow&15. Bias window 191 values, 4 phases
// stride 200 (== 8 mod 32 banks); Xm3 = 124+iloc-jl in [0,187].
// Non-diag units: doff >= 128 -> never masked (proof in notes).
// q,k: [bn][S][D] bf16;  vt: [bn][D][S] bf16;  cum: [N][S] f32 (xLOG2E);
// mix out: [b][s][n][d] bf16
// LDS: K/V dbuf [0,65536) (buf b at b*32768: K 16K, V 16K);
//      cum [2][4][200] f32 [65536,71936); combL [2][32] f32 [71936,72192).
// 72192 B x 2 blocks/CU = 144.4 KB <= 160 KB.
// ---------------------------------------------------------------------------
__device__ __forceinline__ void fa_stage(const bf16* __restrict__ k,
                                         const bf16* __restrict__ vt,
                                         const float* __restrict__ cumn,
                                         char* smem, int bn, int i0, int jb,
                                         int buf, int tid) {
  char* dst = smem + buf * 32768;
  // K tile: rows jb..jb+127 (128B each, 8 chunks); slot (row,ch) holds
  // global chunk ch^kk(row), kk = (row&3)|((row>>1)&4). 1024 chunks.
  const char* ksrc = (const char*)(k + ((size_t)bn * S_ + jb) * DH);
#pragma unroll
  for (int t = 0; t < 4; ++t) {
    int c = t * 256 + tid;
    int row = c >> 3, ch = c & 7;
    int cs = ch ^ ((row & 3) | ((row >> 1) & 4));
    async16(ksrc + row * 128 + cs * 16, dst + c * 16);
  }
  // Vt tile: d rows 0..63, cols jb..jb+127 (256B, 16 chunks); slot (d,ch)
  // holds global chunk ch^(d&15). 1024 chunks.
  const char* vsrc = (const char*)(vt + (size_t)bn * DH * S_);
#pragma unroll
  for (int t = 0; t < 4; ++t) {
    int c = t * 256 + tid;
    int row = c >> 4, ch = c & 15;            // row = d index
    int cs = ch ^ (row & 15);
    async16(vsrc + (size_t)row * (S_ * 2) + jb * 2 + cs * 16,
            dst + 16384 + c * 16);
  }
  // cum windows: win[t] = cumn[clamp(i0-jb-127+t)], t<194; 4 phases,
  // stride 200 words (== 8 mod 32 banks).
  if (tid < 194) {
    float* cdst = (float*)(smem + 65536) + buf * 800;  // 4*200
    int base = i0 - jb - 127 + tid;
#pragma unroll
    for (int p = 0; p < 4; ++p) {
      int src = base + p;
      src = src < 0 ? 0 : (src > S_ - 1 ? S_ - 1 : src);
      async4(cumn + src, cdst + p * 200 + tid);
    }
  }
}

__global__ __launch_bounds__(256, 2)
void fa_kernel(const bf16* __restrict__ q, const bf16* __restrict__ k,
               const bf16* __restrict__ vt, const float* __restrict__ cum,
               bf16* __restrict__ mix) {
  __shared__ char smem[72192] __attribute__((aligned(16)));
  float* combL = (float*)(smem + 71936);        // [2][32]

  const int tid = threadIdx.x, lane = tid & 63, w = tid >> 6;  // w: 0..3
  const int lr = lane & 15, lq = lane >> 4;
  const int rg = w & 1, jh = w >> 1;            // row-group, j-half (64 cols)

  const int L = blockIdx.x;                     // 0..511
  const int xcd = L & 7, slot = L >> 3;         // slot 0..63
  const int bn = xcd + 8 * (slot & 3);          // 4 heads per XCD
  const int pp = slot >> 2;                     // pair index 0..15
  const int n = bn & (NH - 1);
  const int b = bn >> 4;
  const float* cumn = cum + n * S_;

  const int T0 = 31 - pp;                       // heavy tile
  const int T1 = pp;                            // light tile
  const int nu0 = (T0 + 2) >> 1;                // units in tile 0

  // all-ones B fragment for the l row-sum MFMA
  bf16x8 ones;
#pragma unroll
  for (int u = 0; u < 8; ++u) ones[u] = (short)0x3F80;
  const f32x4 fz = {0.f, 0.f, 0.f, 0.f};

  // permuted-K swizzle key (independent of kt/nt2)
  const int kkey = (lr & 3) | (((lr >> 2) & 1) << 2);

  bf16x8 qf[2][2];
  f32x4 oacc[2][4];                             // [is][dt]
  f32x4 lacc[2];

  // prologue: stage unit 0 (tile T0, jt 0) into buf 0
  fa_stage(k, vt, cumn, smem, bn, T0 * 64, 0, 0, tid);

  int ti = T0, jt = 0, i0 = T0 * 64, nu = nu0;

  for (int g = 0; g < 17; ++g) {
    const int bsel = g & 1;
    const char* kb = smem + bsel * 32768;
    const char* vb = kb + 16384;
    const float* cumB = (const float*)(smem + 65536) + bsel * 800;
    const int jb = jt * 128;
    const bool diag = (jt == nu - 1);           // last unit of this tile

    __syncthreads();   // staged data for g visible; buf^1 prior reads done

    // prefetch unit g+1 into the other buffer (flies during this compute)
    if (g + 1 < 17) {
      int gn = g + 1, tin, jtn;
      if (gn < nu0) { tin = T0; jtn = gn; }
      else          { tin = T1; jtn = gn - nu0; }
      fa_stage(k, vt, cumn, smem, bn, tin * 64, jtn * 128, bsel ^ 1, tid);
    }

    if (jt == 0) {
      // new tile: load Q fragments (B-operand for S^T = K*Q^T), reset acc
      const bf16* qbase = q + ((size_t)bn * S_ + i0 + rg * 32) * DH;
#pragma unroll
      for (int is = 0; is < 2; ++is) {
#pragma unroll
        for (int kd = 0; kd < 2; ++kd)
          qf[is][kd] = *(const bf16x8*)(qbase + (is * 16 + lr) * DH + kd * 32 + lq * 8);
        lacc[is] = fz;
#pragma unroll
        for (int dt = 0; dt < 4; ++dt) oacc[is][dt] = fz;
      }
    }

    // S^T = K * Q^T with PERMUTED K rows. MFMA (kt,nt2): A-row lr loads
    // krow = jh*64 + kt*32 + (lr>>2)*8 + nt2*4 + (lr&3) so C position
    // (lq*4+r) holds j = jh*64 + kt*32 + lq*8 + nt2*4 + r — the PV
    // A-fragment layout for k-chunk kt.
    f32x4 sa[2][4] = {};
#pragma unroll
    for (int kd = 0; kd < 2; ++kd)
#pragma unroll
      for (int mm = 0; mm < 4; ++mm) {
        int kt = mm >> 1, nt2 = mm & 1;
        int krow = jh * 64 + kt * 32 + ((lr >> 2) << 3) + nt2 * 4 + (lr & 3);
        bf16x8 kf = *(const bf16x8*)(kb + krow * 128 +
                        (((kd * 4 + lq) ^ kkey) << 4));
        sa[0][mm] = MFMA16(kf, qf[0][kd], sa[0][mm]);
        sa[1][mm] = MFMA16(kf, qf[1][kd], sa[1][mm]);
      }

    // p = exp2(s*SCALE2 + cum[i-j]) straight into PV A-fragments.
    // One b128 bias read per reg-quad: Xm3 = 124+ilocI-jl, cv[m]=win[Xm3+m],
    // bias(r) = cv[3-r].
    const int doff = i0 - jb;                   // diag: 0 or 64; else >=128
    bf16x8 pf[2][2];                            // [is][kt]
#pragma unroll
    for (int is = 0; is < 2; ++is) {
      const int ilocI = rg * 32 + is * 16 + lr; // 0..63
#pragma unroll
      for (int mm = 0; mm < 4; ++mm) {
        int kt = mm >> 1, nt2 = mm & 1;
        int jl = jh * 64 + kt * 32 + lq * 8 + nt2 * 4;
        int Xm3 = 124 + ilocI - jl;
        int ph = Xm3 & 3, b0 = Xm3 & ~3;
        f32x4 cv = *(const f32x4*)(cumB + ph * 200 + b0);
        if (!diag) {
#pragma unroll
          for (int r = 0; r < 4; ++r)
            pf[is][kt][nt2 * 4 + r] =
                bf16bits(exp2f(sa[is][mm][r] * SCALE2 + cv[3 - r]));
        } else {
#pragma unroll
          for (int r = 0; r < 4; ++r) {
            float pv = (doff + ilocI - jl - r >= 0)
                           ? exp2f(sa[is][mm][r] * SCALE2 + cv[3 - r])
                           : 0.f;
            pf[is][kt][nt2 * 4 + r] = bf16bits(pv);
          }
        }
      }
    }

    // O += P V; l += P 1 — pf straight from registers, no LDS.
#pragma unroll
    for (int kt = 0; kt < 2; ++kt) {
      lacc[0] = MFMA16(pf[0][kt], ones, lacc[0]);
      lacc[1] = MFMA16(pf[1][kt], ones, lacc[1]);
#pragma unroll
      for (int dt = 0; dt < 4; ++dt) {
        int vrow = dt * 16 + lr;
        bf16x8 vf = *(const bf16x8*)(vb + vrow * 256 +
                        (((jh * 8 + kt * 4 + lq) ^ (vrow & 15)) << 4));
        oacc[0][dt] = MFMA16(pf[0][kt], vf, oacc[0][dt]);
        oacc[1][dt] = MFMA16(pf[1][kt], vf, oacc[1][dt]);
      }
    }

    if (diag) {
      // tile end: combine j-halves. jh=1 waves export partials into the
      // just-consumed K/V buffer (32KB, free after this barrier).
      __syncthreads();   // all reads of buf bsel complete
      float* scr = (float*)(smem + bsel * 32768) + rg * 2048;  // [32][64]
      if (jh == 1) {
#pragma unroll
        for (int is = 0; is < 2; ++is) {
#pragma unroll
          for (int dt = 0; dt < 4; ++dt)
#pragma unroll
            for (int r = 0; r < 4; ++r) {
              int row = is * 16 + lq * 4 + r;
              int col = ((dt ^ lq) << 4) + lr;   // 2-way-max bank pattern
              scr[row * 64 + col] = oacc[is][dt][r];
            }
          if (lr == 0)
#pragma unroll
            for (int r = 0; r < 4; ++r)
              combL[rg * 32 + is * 16 + lq * 4 + r] = lacc[is][r];
        }
      }
      __syncthreads();   // partials visible
      if (jh == 0) {
#pragma unroll
        for (int is = 0; is < 2; ++is) {
#pragma unroll
          for (int r = 0; r < 4; ++r)
            lacc[is][r] += combL[rg * 32 + is * 16 + lq * 4 + r];
#pragma unroll
          for (int dt = 0; dt < 4; ++dt)
#pragma unroll
            for (int r = 0; r < 4; ++r) {
              int row = is * 16 + lq * 4 + r;
              int col = ((dt ^ lq) << 4) + lr;
              oacc[is][dt][r] += scr[row * 64 + col];
            }
        }
        // store mix[b][s][n][d] for this tile's rows (rg covers 32 rows)
#pragma unroll
        for (int is = 0; is < 2; ++is)
#pragma unroll
          for (int dt = 0; dt < 4; ++dt)
#pragma unroll
            for (int r = 0; r < 4; ++r) {
              int i = i0 + rg * 32 + is * 16 + lq * 4 + r;
              int d = dt * 16 + lr;
              mix[((size_t)(b * S_ + i) * NH + n) * DH + d] =
                  __float2bfloat16(oacc[is][dt][r] / lacc[is][r]);
            }
      }
      ti = T1; jt = 0; i0 = T1 * 64; nu = (T1 + 2) >> 1;  // light tile
    } else {
      ++jt;
    }
  }
}

// ---------------------------------------------------------------------------
extern "C" void kernel_launch(void* const* d_in, const int* in_sizes, int n_in,
                              void* d_out, int out_size, void* d_ws, size_t ws_size,
                              hipStream_t stream) {
  const float* x     = (const float*)d_in[0];   // [B,S,H] f32
  const float* qkv   = (const float*)d_in[1];   // [H,3,N,D] f32 == [1024][3072]
  const float* out_w = (const float*)d_in[2];   // [N,D,H] f32   == [1024][1024]
  const float* rpe   = (const float*)d_in[3];   // [N,S] f32
  float* out = (float*)d_out;                   // [B,S,H] f32

  char* ws = (char*)d_ws;
  bf16* qkvT  = (bf16*)(ws + 0);          // [3072][1024] bf16   6291456 B
  bf16* outwT = (bf16*)(ws + 6291456);    // [1024][1024] bf16   2097152 B
  bf16* xb    = (bf16*)(ws + 8388608);    // [4096][1024] bf16   8388608 B
  bf16* qb    = (bf16*)(ws + 16777216);   // [bn][S][D]          8388608 B
  bf16* kb    = (bf16*)(ws + 25165824);   // [bn][S][D]          8388608 B
  bf16* vtb   = (bf16*)(ws + 33554432);   // [bn][D][S]          8388608 B
  bf16* mixb  = (bf16*)(ws + 41943040);   // [b][s][n][d]        8388608 B
  float* cum  = (float*)(ws + 50331648);  // [N][S] f32 (xLOG2E)  131072 B

  // 1. fused prep: convert x, transpose+convert weights, rpe cumsum
  prep<<<8208, 256, 0, stream>>>(x, xb, qkv, qkvT, out_w, outwT, rpe, cum);
  // 2. QKV projection (BK=64; V written pre-transposed; 768 blocks = 3/CU)
  gemm_bt<0><<<dim3(3072 / 128, 4096 / 128), 256, 0, stream>>>(xb, qkvT, qb, kb, vtb, nullptr);
  // 3. attention: 512 blocks, each exactly 17 64x128-units (pair {31-p,p}),
  //    2 blocks/CU equal-duration, dbuf, in-register P via permuted K rows
  fa_kernel<<<512, 256, 0, stream>>>(qb, kb, vtb, cum, mixb);
  // 4. output projection (BK=64; f32 out; 128x64 tiles -> 512 blocks = 2/CU)
  gemm_bt<1><<<dim3(1024 / 64, 4096 / 128), 256, 0, stream>>>(mixb, outwT, nullptr, nullptr, nullptr, out);
}

// Round 8
// 178.258 us; speedup vs baseline: 1.1535x; 1.0016x over previous
//
#include <hip/hip_runtime.h>
#include <hip/hip_bf16.h>
#include <cstdint>
#include <cstddef>

// Problem constants
#define B_   2
#define S_   2048
#define H_   1024
#define NH   16
#define DH   64
#define LOG2E 1.4426950408889634f
#define SCALE2 (0.125f * LOG2E)   // D^-0.5 * log2(e): softmax done in exp2 domain

typedef __hip_bfloat16 bf16;
typedef short bf16x8 __attribute__((ext_vector_type(8)));   // 8 bf16 in 4 VGPRs
typedef float f32x4 __attribute__((ext_vector_type(4)));

#define MFMA16(a, b, c) __builtin_amdgcn_mfma_f32_16x16x32_bf16((a), (b), (c), 0, 0, 0)

__device__ __forceinline__ void async16(const void* g, void* l) {
  __builtin_amdgcn_global_load_lds(
      (const __attribute__((address_space(1))) void*)g,
      (__attribute__((address_space(3))) void*)l,
      16, 0, 0);
}
__device__ __forceinline__ void async4(const void* g, void* l) {
  __builtin_amdgcn_global_load_lds(
      (const __attribute__((address_space(1))) void*)g,
      (__attribute__((address_space(3))) void*)l,
      4, 0, 0);
}

__device__ __forceinline__ short bf16bits(float v) {
  bf16 t = __float2bfloat16(v);
  return *reinterpret_cast<short*>(&t);
}

// ---------------------------------------------------------------------------
// Fused prep kernel (one dispatch, grid 8208) — unchanged.
// ---------------------------------------------------------------------------
__device__ __forceinline__ void tr_body(const float* __restrict__ src,
                                        bf16* __restrict__ dst, int R, int C,
                                        int c0, int r0, bf16 (*tile)[33], int tid) {
  int tx = tid & 31, ty = tid >> 5;   // 32 x 8
  for (int i = 0; i < 32; i += 8)
    tile[ty + i][tx] = __float2bfloat16(src[(size_t)(r0 + ty + i) * C + c0 + tx]);
  __syncthreads();
  for (int i = 0; i < 32; i += 8)
    dst[(size_t)(c0 + ty + i) * R + r0 + tx] = tile[tx][ty + i];
}

__global__ __launch_bounds__(256)
void prep(const float* __restrict__ x, bf16* __restrict__ xb,
          const float* __restrict__ qkv, bf16* __restrict__ qkvT,
          const float* __restrict__ outw, bf16* __restrict__ outwT,
          const float* __restrict__ rpe, float* __restrict__ cum) {
  __shared__ char pm[2176] __attribute__((aligned(16)));
  const int L = blockIdx.x, tid = threadIdx.x;
  if (L < 4096) {
    int i = (L * 256 + tid) * 4;
    float4 v = *(const float4*)(x + i);
    bf16 o[4] = {__float2bfloat16(v.x), __float2bfloat16(v.y),
                 __float2bfloat16(v.z), __float2bfloat16(v.w)};
    *(uint64_t*)(xb + i) = *(const uint64_t*)o;
  } else if (L < 7168) {
    int t = L - 4096;
    int cx = t % 96, ry = t / 96;
    tr_body(qkv, qkvT, 1024, 3072, cx * 32, ry * 32, (bf16(*)[33])pm, tid);
  } else if (L < 8192) {
    int t = L - 7168;
    int cx = t & 31, ry = t >> 5;
    tr_body(outw, outwT, 1024, 1024, cx * 32, ry * 32, (bf16(*)[33])pm, tid);
  } else {
    // rpe cumsum (scaled by LOG2E)
    float* ssum = (float*)pm;
    int n = L - 8192;
    float loc[8];
    float s = 0.f;
    int base = tid * 8;
#pragma unroll
    for (int u = 0; u < 8; ++u) {
      loc[u] = rpe[n * S_ + base + u];
      s += loc[u];
    }
    ssum[tid] = s;
    __syncthreads();
    float own = s;
    for (int off = 1; off < 256; off <<= 1) {
      float v = (tid >= off) ? ssum[tid - off] : 0.f;
      __syncthreads();
      ssum[tid] += v;
      __syncthreads();
    }
    float run = ssum[tid] - own;   // exclusive prefix of this thread's chunk
#pragma unroll
    for (int u = 0; u < 8; ++u) {
      run += loc[u];
      cum[n * S_ + base + u] = run * LOG2E;
    }
  }
}

// ---------------------------------------------------------------------------
// GEMM: C[M x Nc] = A[M x 1024] * Bt[Nc x 1024]^T, bf16 in, f32 acc.
// R8: DOUBLE-BUFFERED staging with ONE barrier per K-step (fa's proven
// pattern). Old loop: barrier -> issue global_load_lds -> barrier(vmcnt(0)
// drain) -> compute: the drain immediately follows the issue, exposing the
// full HBM latency EVERY K-step. New: stage(buf s+1) issued right after the
// step-s barrier flies under step-s compute; the drain at the s+1 barrier
// finds the loads landed. BK=32, 32 steps; MODE0 dbuf 32KB < 36.9KB
// epilogue region -> LDS unchanged, 3 blocks/CU KEPT (m132: 64KB -> 2/CU
// regresses). MODE1 dbuf 24KB, 2/CU. Swizzle (R0-proven, 64B rows):
// slot(row,ch) holds chunk ch^((row>>1)&3); read chunk lq^((row>>1)&3).
// ---------------------------------------------------------------------------
template <int MODE>
__global__ __launch_bounds__(256, MODE == 0 ? 3 : 2)
void gemm_bt(const bf16* __restrict__ A, const bf16* __restrict__ Bt,
             bf16* __restrict__ C0, bf16* __restrict__ C1, bf16* __restrict__ C2,
             float* __restrict__ F0) {
  constexpr int NT = (MODE == 0) ? 4 : 2;     // n-subtiles per wave
  constexpr int NB = NT * 32;                 // block n-extent: 128 or 64
  constexpr int BUFSZ = 8192 + NB * 64;       // A 8KB + B NB*32*2B
  __shared__ char smem[MODE == 0 ? 36864 : 24576] __attribute__((aligned(16)));
  const int tid = threadIdx.x, lane = tid & 63, w = tid >> 6;
  const int lr = lane & 15, lq = lane >> 4;
  const int m0 = blockIdx.y * 128, n0 = blockIdx.x * NB;
  const int wm = (w & 1) * 64, wn = (w >> 1) * (NT * 16);

  f32x4 acc[4][NT] = {};

  auto stage = [&](int buf, int k0) {
    char* dst = smem + buf * BUFSZ;
    // A tile: 128 rows x 32 bf16 (4 chunks/row) = 512 chunks, 2/thread
#pragma unroll
    for (int t = 0; t < 2; ++t) {
      int c = t * 256 + tid;
      int row = c >> 2, ch = c & 3;
      int k8 = (ch ^ ((row >> 1) & 3)) * 8;
      async16(A + (size_t)(m0 + row) * 1024 + k0 + k8, dst + c * 16);
    }
    // B tile: NB rows x 32 bf16
#pragma unroll
    for (int t = 0; t < NB / 64; ++t) {
      int c = t * 256 + tid;
      int row = c >> 2, ch = c & 3;
      int k8 = (ch ^ ((row >> 1) & 3)) * 8;
      async16(Bt + (size_t)(n0 + row) * 1024 + k0 + k8, dst + 8192 + c * 16);
    }
  };

  // prologue: stage step 0 into buf 0
  stage(0, 0);

  for (int s = 0; s < 32; ++s) {
    const int bsel = s & 1;
    __syncthreads();   // buf[bsel] staged (own vmcnt drained at barrier);
                       // prior ds reads of buf[bsel^1] done (lgkm drained)

    // prefetch step s+1 into the other buffer (flies under this compute)
    if (s + 1 < 32) stage(bsel ^ 1, (s + 1) * 32);

    const bf16* As = (const bf16*)(smem + bsel * BUFSZ);
    const bf16* Bs = (const bf16*)(smem + bsel * BUFSZ + 8192);
    bf16x8 af[4], bfr[NT];
#pragma unroll
    for (int mt = 0; mt < 4; ++mt) {
      int row = wm + mt * 16 + lr;
      af[mt] = *(const bf16x8*)(As + row * 32 + ((lq ^ ((row >> 1) & 3)) << 3));
    }
#pragma unroll
    for (int nt = 0; nt < NT; ++nt) {
      int row = wn + nt * 16 + lr;
      bfr[nt] = *(const bf16x8*)(Bs + row * 32 + ((lq ^ ((row >> 1) & 3)) << 3));
    }
#pragma unroll
    for (int mt = 0; mt < 4; ++mt)
#pragma unroll
      for (int nt = 0; nt < NT; ++nt)
        acc[mt][nt] = MFMA16(af[mt], bfr[nt], acc[mt][nt]);
  }

  if (MODE == 0) {
    __syncthreads();   // all As/Bs reads done; reuse LDS for epilogue tiles
    bf16* E = (bf16*)smem + w * (64 * 72);   // wave-private [64][72]
    const int cbase = n0 + wn;               // 64-aligned
    const int mm = cbase >> 10, nn = (cbase >> 6) & 15;
    const int bb = (m0 + wm) >> 11;
    const int sbase = (m0 + wm) & 2047;
    if (mm < 2) {
      // write acc as [s][d] into E
#pragma unroll
      for (int mt = 0; mt < 4; ++mt)
#pragma unroll
        for (int nt = 0; nt < 4; ++nt)
#pragma unroll
          for (int r = 0; r < 4; ++r)
            E[(mt * 16 + lq * 4 + r) * 72 + nt * 16 + lr] =
                __float2bfloat16(acc[mt][nt][r]);
      // wave-private readback (in-wave lgkm ordering), b128 stores
      bf16* dst = (mm == 0 ? C0 : C1) +
                  ((size_t)(bb * NH + nn) * S_ + sbase) * DH;
#pragma unroll
      for (int it = 0; it < 8; ++it) {
        int c = it * 64 + lane;
        int rw = c >> 3, c8 = c & 7;
        *(uint4*)(dst + (size_t)rw * DH + c8 * 8) =
            *(const uint4*)(E + rw * 72 + c8 * 8);
      }
    } else {
      // V: write acc as [d][s] into E
#pragma unroll
      for (int mt = 0; mt < 4; ++mt)
#pragma unroll
        for (int nt = 0; nt < 4; ++nt)
#pragma unroll
          for (int r = 0; r < 4; ++r)
            E[(nt * 16 + lr) * 72 + mt * 16 + lq * 4 + r] =
                __float2bfloat16(acc[mt][nt][r]);
      bf16* dst = C2 + (size_t)(bb * NH + nn) * DH * S_;
#pragma unroll
      for (int it = 0; it < 8; ++it) {
        int c = it * 64 + lane;
        int dr = c >> 3, c8 = c & 7;
        *(uint4*)(dst + (size_t)dr * S_ + sbase + c8 * 8) =
            *(const uint4*)(E + dr * 72 + c8 * 8);
      }
    }
  } else {
#pragma unroll
    for (int mt = 0; mt < 4; ++mt)
#pragma unroll
      for (int nt = 0; nt < NT; ++nt)
#pragma unroll
        for (int r = 0; r < 4; ++r) {
          int rM = m0 + wm + mt * 16 + lq * 4 + r;
          int cN = n0 + wn + nt * 16 + lr;
          F0[(size_t)rM * 1024 + cN] = acc[mt][nt][r];
        }
  }
}

// ---------------------------------------------------------------------------
// Flash attention — unchanged from R7 (the control for this round).
// 128-col KV units, in-register P via permuted K rows, equal-duration
// pairing {31-p, p} = 17 units, dbuf prefetch, single barrier/unit.
// LDS: K/V dbuf [0,65536); cum [2][4][200] f32 [65536,71936);
//      combL [2][32] f32 [71936,72192). 72192 x 2 blocks/CU <= 160 KB.
// ---------------------------------------------------------------------------
__device__ __forceinline__ void fa_stage(const bf16* __restrict__ k,
                                         const bf16* __restrict__ vt,
                                         const float* __restrict__ cumn,
                                         char* smem, int bn, int i0, int jb,
                                         int buf, int tid) {
  char* dst = smem + buf * 32768;
  // K tile: rows jb..jb+127 (128B each, 8 chunks); slot (row,ch) holds
  // global chunk ch^kk(row), kk = (row&3)|((row>>1)&4). 1024 chunks.
  const char* ksrc = (const char*)(k + ((size_t)bn * S_ + jb) * DH);
#pragma unroll
  for (int t = 0; t < 4; ++t) {
    int c = t * 256 + tid;
    int row = c >> 3, ch = c & 7;
    int cs = ch ^ ((row & 3) | ((row >> 1) & 4));
    async16(ksrc + row * 128 + cs * 16, dst + c * 16);
  }
  // Vt tile: d rows 0..63, cols jb..jb+127 (256B, 16 chunks); slot (d,ch)
  // holds global chunk ch^(d&15). 1024 chunks.
  const char* vsrc = (const char*)(vt + (size_t)bn * DH * S_);
#pragma unroll
  for (int t = 0; t < 4; ++t) {
    int c = t * 256 + tid;
    int row = c >> 4, ch = c & 15;            // row = d index
    int cs = ch ^ (row & 15);
    async16(vsrc + (size_t)row * (S_ * 2) + jb * 2 + cs * 16,
            dst + 16384 + c * 16);
  }
  // cum windows: win[t] = cumn[clamp(i0-jb-127+t)], t<194; 4 phases,
  // stride 200 words (== 8 mod 32 banks).
  if (tid < 194) {
    float* cdst = (float*)(smem + 65536) + buf * 800;  // 4*200
    int base = i0 - jb - 127 + tid;
#pragma unroll
    for (int p = 0; p < 4; ++p) {
      int src = base + p;
      src = src < 0 ? 0 : (src > S_ - 1 ? S_ - 1 : src);
      async4(cumn + src, cdst + p * 200 + tid);
    }
  }
}

__global__ __launch_bounds__(256, 2)
void fa_kernel(const bf16* __restrict__ q, const bf16* __restrict__ k,
               const bf16* __restrict__ vt, const float* __restrict__ cum,
               bf16* __restrict__ mix) {
  __shared__ char smem[72192] __attribute__((aligned(16)));
  float* combL = (float*)(smem + 71936);        // [2][32]

  const int tid = threadIdx.x, lane = tid & 63, w = tid >> 6;  // w: 0..3
  const int lr = lane & 15, lq = lane >> 4;
  const int rg = w & 1, jh = w >> 1;            // row-group, j-half (64 cols)

  const int L = blockIdx.x;                     // 0..511
  const int xcd = L & 7, slot = L >> 3;         // slot 0..63
  const int bn = xcd + 8 * (slot & 3);          // 4 heads per XCD
  const int pp = slot >> 2;                     // pair index 0..15
  const int n = bn & (NH - 1);
  const int b = bn >> 4;
  const float* cumn = cum + n * S_;

  const int T0 = 31 - pp;                       // heavy tile
  const int T1 = pp;                            // light tile
  const int nu0 = (T0 + 2) >> 1;                // units in tile 0

  // all-ones B fragment for the l row-sum MFMA
  bf16x8 ones;
#pragma unroll
  for (int u = 0; u < 8; ++u) ones[u] = (short)0x3F80;
  const f32x4 fz = {0.f, 0.f, 0.f, 0.f};

  // permuted-K swizzle key (independent of kt/nt2)
  const int kkey = (lr & 3) | (((lr >> 2) & 1) << 2);

  bf16x8 qf[2][2];
  f32x4 oacc[2][4];                             // [is][dt]
  f32x4 lacc[2];

  // prologue: stage unit 0 (tile T0, jt 0) into buf 0
  fa_stage(k, vt, cumn, smem, bn, T0 * 64, 0, 0, tid);

  int ti = T0, jt = 0, i0 = T0 * 64, nu = nu0;

  for (int g = 0; g < 17; ++g) {
    const int bsel = g & 1;
    const char* kb = smem + bsel * 32768;
    const char* vb = kb + 16384;
    const float* cumB = (const float*)(smem + 65536) + bsel * 800;
    const int jb = jt * 128;
    const bool diag = (jt == nu - 1);           // last unit of this tile

    __syncthreads();   // staged data for g visible; buf^1 prior reads done

    // prefetch unit g+1 into the other buffer (flies during this compute)
    if (g + 1 < 17) {
      int gn = g + 1, tin, jtn;
      if (gn < nu0) { tin = T0; jtn = gn; }
      else          { tin = T1; jtn = gn - nu0; }
      fa_stage(k, vt, cumn, smem, bn, tin * 64, jtn * 128, bsel ^ 1, tid);
    }

    if (jt == 0) {
      // new tile: load Q fragments (B-operand for S^T = K*Q^T), reset acc
      const bf16* qbase = q + ((size_t)bn * S_ + i0 + rg * 32) * DH;
#pragma unroll
      for (int is = 0; is < 2; ++is) {
#pragma unroll
        for (int kd = 0; kd < 2; ++kd)
          qf[is][kd] = *(const bf16x8*)(qbase + (is * 16 + lr) * DH + kd * 32 + lq * 8);
        lacc[is] = fz;
#pragma unroll
        for (int dt = 0; dt < 4; ++dt) oacc[is][dt] = fz;
      }
    }

    // S^T = K * Q^T with PERMUTED K rows. MFMA (kt,nt2): A-row lr loads
    // krow = jh*64 + kt*32 + (lr>>2)*8 + nt2*4 + (lr&3) so C position
    // (lq*4+r) holds j = jh*64 + kt*32 + lq*8 + nt2*4 + r — the PV
    // A-fragment layout for k-chunk kt.
    f32x4 sa[2][4] = {};
#pragma unroll
    for (int kd = 0; kd < 2; ++kd)
#pragma unroll
      for (int mm = 0; mm < 4; ++mm) {
        int kt = mm >> 1, nt2 = mm & 1;
        int krow = jh * 64 + kt * 32 + ((lr >> 2) << 3) + nt2 * 4 + (lr & 3);
        bf16x8 kf = *(const bf16x8*)(kb + krow * 128 +
                        (((kd * 4 + lq) ^ kkey) << 4));
        sa[0][mm] = MFMA16(kf, qf[0][kd], sa[0][mm]);
        sa[1][mm] = MFMA16(kf, qf[1][kd], sa[1][mm]);
      }

    // p = exp2(s*SCALE2 + cum[i-j]) straight into PV A-fragments.
    // One b128 bias read per reg-quad: Xm3 = 124+ilocI-jl, cv[m]=win[Xm3+m],
    // bias(r) = cv[3-r].
    const int doff = i0 - jb;                   // diag: 0 or 64; else >=128
    bf16x8 pf[2][2];                            // [is][kt]
#pragma unroll
    for (int is = 0; is < 2; ++is) {
      const int ilocI = rg * 32 + is * 16 + lr; // 0..63
#pragma unroll
      for (int mm = 0; mm < 4; ++mm) {
        int kt = mm >> 1, nt2 = mm & 1;
        int jl = jh * 64 + kt * 32 + lq * 8 + nt2 * 4;
        int Xm3 = 124 + ilocI - jl;
        int ph = Xm3 & 3, b0 = Xm3 & ~3;
        f32x4 cv = *(const f32x4*)(cumB + ph * 200 + b0);
        if (!diag) {
#pragma unroll
          for (int r = 0; r < 4; ++r)
            pf[is][kt][nt2 * 4 + r] =
                bf16bits(exp2f(sa[is][mm][r] * SCALE2 + cv[3 - r]));
        } else {
#pragma unroll
          for (int r = 0; r < 4; ++r) {
            float pv = (doff + ilocI - jl - r >= 0)
                           ? exp2f(sa[is][mm][r] * SCALE2 + cv[3 - r])
                           : 0.f;
            pf[is][kt][nt2 * 4 + r] = bf16bits(pv);
          }
        }
      }
    }

    // O += P V; l += P 1 — pf straight from registers, no LDS.
#pragma unroll
    for (int kt = 0; kt < 2; ++kt) {
      lacc[0] = MFMA16(pf[0][kt], ones, lacc[0]);
      lacc[1] = MFMA16(pf[1][kt], ones, lacc[1]);
#pragma unroll
      for (int dt = 0; dt < 4; ++dt) {
        int vrow = dt * 16 + lr;
        bf16x8 vf = *(const bf16x8*)(vb + vrow * 256 +
                        (((jh * 8 + kt * 4 + lq) ^ (vrow & 15)) << 4));
        oacc[0][dt] = MFMA16(pf[0][kt], vf, oacc[0][dt]);
        oacc[1][dt] = MFMA16(pf[1][kt], vf, oacc[1][dt]);
      }
    }

    if (diag) {
      // tile end: combine j-halves. jh=1 waves export partials into the
      // just-consumed K/V buffer (32KB, free after this barrier).
      __syncthreads();   // all reads of buf bsel complete
      float* scr = (float*)(smem + bsel * 32768) + rg * 2048;  // [32][64]
      if (jh == 1) {
#pragma unroll
        for (int is = 0; is < 2; ++is) {
#pragma unroll
          for (int dt = 0; dt < 4; ++dt)
#pragma unroll
            for (int r = 0; r < 4; ++r) {
              int row = is * 16 + lq * 4 + r;
              int col = ((dt ^ lq) << 4) + lr;   // 2-way-max bank pattern
              scr[row * 64 + col] = oacc[is][dt][r];
            }
          if (lr == 0)
#pragma unroll
            for (int r = 0; r < 4; ++r)
              combL[rg * 32 + is * 16 + lq * 4 + r] = lacc[is][r];
        }
      }
      __syncthreads();   // partials visible
      if (jh == 0) {
#pragma unroll
        for (int is = 0; is < 2; ++is) {
#pragma unroll
          for (int r = 0; r < 4; ++r)
            lacc[is][r] += combL[rg * 32 + is * 16 + lq * 4 + r];
#pragma unroll
          for (int dt = 0; dt < 4; ++dt)
#pragma unroll
            for (int r = 0; r < 4; ++r) {
              int row = is * 16 + lq * 4 + r;
              int col = ((dt ^ lq) << 4) + lr;
              oacc[is][dt][r] += scr[row * 64 + col];
            }
        }
        // store mix[b][s][n][d] for this tile's rows (rg covers 32 rows)
#pragma unroll
        for (int is = 0; is < 2; ++is)
#pragma unroll
          for (int dt = 0; dt < 4; ++dt)
#pragma unroll
            for (int r = 0; r < 4; ++r) {
              int i = i0 + rg * 32 + is * 16 + lq * 4 + r;
              int d = dt * 16 + lr;
              mix[((size_t)(b * S_ + i) * NH + n) * DH + d] =
                  __float2bfloat16(oacc[is][dt][r] / lacc[is][r]);
            }
      }
      ti = T1; jt = 0; i0 = T1 * 64; nu = (T1 + 2) >> 1;  // light tile
    } else {
      ++jt;
    }
  }
}

// ---------------------------------------------------------------------------
extern "C" void kernel_launch(void* const* d_in, const int* in_sizes, int n_in,
                              void* d_out, int out_size, void* d_ws, size_t ws_size,
                              hipStream_t stream) {
  const float* x     = (const float*)d_in[0];   // [B,S,H] f32
  const float* qkv   = (const float*)d_in[1];   // [H,3,N,D] f32 == [1024][3072]
  const float* out_w = (const float*)d_in[2];   // [N,D,H] f32   == [1024][1024]
  const float* rpe   = (const float*)d_in[3];   // [N,S] f32
  float* out = (float*)d_out;                   // [B,S,H] f32

  char* ws = (char*)d_ws;
  bf16* qkvT  = (bf16*)(ws + 0);          // [3072][1024] bf16   6291456 B
  bf16* outwT = (bf16*)(ws + 6291456);    // [1024][1024] bf16   2097152 B
  bf16* xb    = (bf16*)(ws + 8388608);    // [4096][1024] bf16   8388608 B
  bf16* qb    = (bf16*)(ws + 16777216);   // [bn][S][D]          8388608 B
  bf16* kb    = (bf16*)(ws + 25165824);   // [bn][S][D]          8388608 B
  bf16* vtb   = (bf16*)(ws + 33554432);   // [bn][D][S]          8388608 B
  bf16* mixb  = (bf16*)(ws + 41943040);   // [b][s][n][d]        8388608 B
  float* cum  = (float*)(ws + 50331648);  // [N][S] f32 (xLOG2E)  131072 B

  // 1. fused prep: convert x, transpose+convert weights, rpe cumsum
  prep<<<8208, 256, 0, stream>>>(x, xb, qkv, qkvT, out_w, outwT, rpe, cum);
  // 2. QKV projection (dbuf single-barrier; V pre-transposed; 768 blocks)
  gemm_bt<0><<<dim3(3072 / 128, 4096 / 128), 256, 0, stream>>>(xb, qkvT, qb, kb, vtb, nullptr);
  // 3. attention (unchanged R7): 512 blocks, 17 64x128-units each
  fa_kernel<<<512, 256, 0, stream>>>(qb, kb, vtb, cum, mixb);
  // 4. output projection (dbuf single-barrier; f32 out; 512 blocks = 2/CU)
  gemm_bt<1><<<dim3(1024 / 64, 4096 / 128), 256, 0, stream>>>(mixb, outwT, nullptr, nullptr, nullptr, out);
}